// Round 16
// baseline (9883.186 us; speedup 1.0000x reference)
//
#include <hip/hip_runtime.h>

// Seq2Seq forward. R16: W2 algebraically folded into the decoder recurrence
// (gates_x = ge[i] + z @ Wfold^T, Wfold = Wih_out @ W2^T precomputed once;
// per-step emb terms ge[64][2048] precomputed) -> xdec eliminated, P5 leaves
// the dependence cycle, barrier count 5 -> 4 per step. Decoder else = R15
// (persistent cell weights, z-h-half in P2, flash P3). Encoder = R14 pipeline.

#define DI __device__ __forceinline__

constexpr int BATCH = 32;
constexpr int TS = 1024;
constexpr int TG = 64;
constexpr int HID = 512;
constexpr int GD = 2048;
constexpr int EDIM = 256;
constexpr int SPECIAL = 4;
constexpr size_t OFF_H = (size_t)BATCH * TG * EDIM;
constexpr size_t OFF_C = OFF_H + (size_t)BATCH * TG * HID;
constexpr int FLAG_STRIDE = 16;   // dwords (64B) per flag

typedef __attribute__((ext_vector_type(8))) short bf16x8;
typedef __attribute__((ext_vector_type(4))) float f32x4;

DI float b2f(unsigned short u) {
  union { unsigned int i; float f; } v; v.i = ((unsigned int)u) << 16; return v.f;
}
DI unsigned short f2b(float f) {
  union { float f; unsigned int i; } v; v.f = f;
  unsigned int r = v.i + 0x7fffu + ((v.i >> 16) & 1u);
  return (unsigned short)(r >> 16);
}
DI float sigm(float x) { return 1.0f / (1.0f + expf(-x)); }
DI float ldf(const void* p, size_t i, int f32f) {
  return f32f ? ((const float*)p)[i] : b2f(((const unsigned short*)p)[i]);
}
DI void stf(void* p, size_t i, float v, int f32f) {
  if (f32f) ((float*)p)[i] = v; else ((unsigned short*)p)[i] = f2b(v);
}
DI unsigned int ald(const unsigned int* p) {
  return __hip_atomic_load(p, __ATOMIC_RELAXED, __HIP_MEMORY_SCOPE_AGENT);
}
DI float aldf(const float* p) {
  return __hip_atomic_load(p, __ATOMIC_RELAXED, __HIP_MEMORY_SCOPE_AGENT);
}
DI void ast(unsigned int* p, unsigned int v) {
  __hip_atomic_store(p, v, __ATOMIC_RELAXED, __HIP_MEMORY_SCOPE_AGENT);
}
DI void astf(float* p, float v) {
  __hip_atomic_store(p, v, __ATOMIC_RELAXED, __HIP_MEMORY_SCOPE_AGENT);
}

__global__ void detect_k(const void* art, int* flag) {
  int tid = threadIdx.x;
  float x = ((const float*)art)[tid + 1024];
  float a = fabsf(x);
  int sane = (x == 0.0f) || (a > 1e-8f && a < 1e4f);
  unsigned long long m = __ballot(sane);
  __shared__ int cnt[4];
  if ((tid & 63) == 0) cnt[tid >> 6] = __popcll(m);
  __syncthreads();
  if (tid == 0) flag[0] = (cnt[0] + cnt[1] + cnt[2] + cnt[3] > 128) ? 1 : 0;
}

__global__ void fill_sig_k(unsigned short* o, int n) {
  int g = blockIdx.x * 256 + threadIdx.x;
  if (g < n) o[g] = 0x42F6;
}

__global__ void pack_gate_k(const void* __restrict__ W,
                            unsigned short* __restrict__ pk, const int* dtf) {
  int f32f = dtf[0];
  int g = blockIdx.x * 256 + threadIdx.x;
  if (g >= (GD * HID) / 8) return;
  int lane = g & 63;
  int kk = (g >> 6) & 15;
  int tile = g >> 10;
  int p = tile * 16 + (lane & 15);
  int nloc = p & 63, blk = p >> 6;
  int orow = (nloc >> 4) * HID + blk * 16 + (nloc & 15);
  int k = kk * 32 + (lane >> 4) * 8;
  unsigned short tmp[8];
#pragma unroll
  for (int j = 0; j < 8; ++j) tmp[j] = f2b(ldf(W, (size_t)orow * HID + k + j, f32f));
  *(uint4*)(pk + (size_t)g * 8) = *(uint4*)tmp;
}

// pack_gate for an internal f32 matrix (Wfold)
__global__ void pack_gate_f32_k(const float* __restrict__ W,
                                unsigned short* __restrict__ pk) {
  int g = blockIdx.x * 256 + threadIdx.x;
  if (g >= (GD * HID) / 8) return;
  int lane = g & 63;
  int kk = (g >> 6) & 15;
  int tile = g >> 10;
  int p = tile * 16 + (lane & 15);
  int nloc = p & 63, blk = p >> 6;
  int orow = (nloc >> 4) * HID + blk * 16 + (nloc & 15);
  int k = kk * 32 + (lane >> 4) * 8;
  unsigned short tmp[8];
#pragma unroll
  for (int j = 0; j < 8; ++j) tmp[j] = f2b(W[(size_t)orow * HID + k + j]);
  *(uint4*)(pk + (size_t)g * 8) = *(uint4*)tmp;
}

__global__ void pack_wm_k(const void* __restrict__ wm,
                          unsigned short* __restrict__ pk, const int* dtf) {
  int f32f = dtf[0];
  int g = blockIdx.x * 256 + threadIdx.x;
  if (g >= 32 * 32 * 64) return;
  int lane = g & 63;
  int kk = (g >> 6) & 31;
  int nt = g >> 11;
  int col = nt * 16 + (lane & 15);
  int kb = kk * 32 + (lane >> 4) * 8;
  unsigned short tmp[8];
#pragma unroll
  for (int j = 0; j < 8; ++j) tmp[j] = f2b(ldf(wm, (size_t)(kb + j) * HID + col, f32f));
  *(uint4*)(pk + (size_t)g * 8) = *(uint4*)tmp;
}

// Generic B-pack: W[K][N] row-major -> pk[(nt*(K/32)+kk)*64+lane][8]
__global__ void pack_bn_k(const void* __restrict__ W, unsigned short* __restrict__ pk,
                          int K, int N, int total, const int* dtf) {
  int f32f = dtf[0];
  int g = blockIdx.x * 256 + threadIdx.x;
  if (g >= total) return;
  int lane = g & 63;
  int KK = K >> 5;
  int t = g >> 6;
  int kk = t % KK;
  int nt = t / KK;
  int col = nt * 16 + (lane & 15);
  int kb = kk * 32 + (lane >> 4) * 8;
  unsigned short tmp[8];
#pragma unroll
  for (int j = 0; j < 8; ++j) tmp[j] = f2b(ldf(W, (size_t)(kb + j) * N + col, f32f));
  *(uint4*)(pk + (size_t)g * 8) = *(uint4*)tmp;
}

__global__ void pack_bf16_k(const void* __restrict__ src,
                            unsigned short* __restrict__ dst, int n, const int* dtf) {
  int f32f = dtf[0];
  int g = blockIdx.x * 256 + threadIdx.x;
  if (g < n) dst[g] = f2b(ldf(src, g, f32f));
}

// Wfold[g][kz] = sum_m Wih[g][256+m] * W2[kz][m]   (f32 out, one block per g)
__global__ void fold_w_k(const void* __restrict__ dWx, const void* __restrict__ W2,
                         float* __restrict__ wf, const int* dtf) {
  int f32f = dtf[0];
  __shared__ float arow[256];
  int g = blockIdx.x;            // 0..2047
  int tid = threadIdx.x;         // 0..255
  arow[tid] = ldf(dWx, (size_t)g * 512 + 256 + tid, f32f);
  __syncthreads();
  float a0 = 0.f, a1 = 0.f;
  for (int m = 0; m < 256; ++m) {
    float a = arow[m];
    a0 += a * ldf(W2, (size_t)tid * 256 + m, f32f);
    a1 += a * ldf(W2, (size_t)(tid + 256) * 256 + m, f32f);
  }
  wf[(size_t)g * 512 + tid] = a0;
  wf[(size_t)g * 512 + tid + 256] = a1;
}

// ge[i][g] = sum_m emb[SPECIAL+i][m] * Wih[g][m]   (i in 0..63)
__global__ void ge_k(const void* __restrict__ emb, const void* __restrict__ dWx,
                     float* __restrict__ ge, const int* dtf) {
  int f32f = dtf[0];
  int idx = blockIdx.x * 256 + threadIdx.x;   // 512 blocks -> 131072
  int i = idx >> 11, g = idx & 2047;
  float a = 0.f;
  for (int m = 0; m < 256; ++m)
    a += ldf(emb, (size_t)(SPECIAL + i) * 256 + m, f32f) *
         ldf(dWx, (size_t)g * 512 + m, f32f);
  ge[(size_t)i * 2048 + g] = a;
}

// ---------------------------------------------------------------------------
// Persistent bidirectional encoder (R14 software pipeline — proven).
// ---------------------------------------------------------------------------
__global__ __launch_bounds__(256, 1) void enc_all_k(
    const unsigned short* __restrict__ artb,
    unsigned short* __restrict__ outF, unsigned short* __restrict__ outB,
    const unsigned short* __restrict__ hIF, const unsigned short* __restrict__ hIB,
    float* __restrict__ cF, float* __restrict__ cB,
    const unsigned short* __restrict__ pkXF, const unsigned short* __restrict__ pkHF,
    const unsigned short* __restrict__ pkXB, const unsigned short* __restrict__ pkHB,
    const void* __restrict__ bF, const void* __restrict__ bB,
    int* __restrict__ bar, const int* dtf) {
  const int f32f = dtf[0];
  const int blk = blockIdx.x;
  const int dir = blk >> 5;
  const int blk16 = blk & 31;
  const int tid = threadIdx.x;
  const int lane = tid & 63;
  const int wv = tid >> 6;
  const int tile = blk16 * 4 + wv;

  __shared__ unsigned short lstage[BATCH * HID];
  __shared__ float gbuf[BATCH * 68];

  const unsigned short* pkX = dir ? pkXB : pkXF;
  const unsigned short* pkH = dir ? pkHB : pkHF;
  const void* bias = dir ? bB : bF;
  unsigned short* out = dir ? outB : outF;
  const unsigned short* hI = dir ? hIB : hIF;
  float* cg = dir ? cB : cF;
  int* flp = bar + dir * 32 * FLAG_STRIDE;

  bf16x8 wx[16], wh[16];
  {
    const unsigned short* px = pkX + ((size_t)tile * 16 * 64 + lane) * 8;
    const unsigned short* ph = pkH + ((size_t)tile * 16 * 64 + lane) * 8;
#pragma unroll
    for (int kk = 0; kk < 16; ++kk) {
      wx[kk] = *(const bf16x8*)(px + (size_t)kk * 64 * 8);
      wh[kk] = *(const bf16x8*)(ph + (size_t)kk * 64 * 8);
    }
  }
  const int gb = tid >> 3;
  const int gj = (tid & 7) * 2;
  float c0 = cg[gb * HID + blk16 * 16 + gj];
  float c1 = cg[gb * HID + blk16 * 16 + gj + 1];

  const int r0 = lane & 15;
  const int r1 = 16 + r0;
  const int kbb = (lane >> 4) * 8;
  const int nloc = wv * 16 + (lane & 15);
  const int orow = (nloc >> 4) * HID + blk16 * 16 + (nloc & 15);
  const float bv = ldf(bias, orow, f32f);

  f32x4 acc0 = {0.f, 0.f, 0.f, 0.f};
  f32x4 acc1 = {0.f, 0.f, 0.f, 0.f};

  {
    const int ts0 = dir ? (TS - 1) : 0;
#pragma unroll
    for (int it = 0; it < 8; ++it) {
      int ci = it * 256 + tid;
      int row = ci >> 6;
      int k8 = (ci & 63) << 3;
      uint4 v = *(const uint4*)(artb + (size_t)ts0 * BATCH * HID +
                                (size_t)row * HID + k8);
      unsigned off = (unsigned)(row * 1024 + ((k8 * 2) ^ ((row & 7) << 4)));
      *(uint4*)((char*)lstage + off) = v;
    }
    __syncthreads();
#pragma unroll
    for (int kk = 0; kk < 16; ++kk) {
      unsigned o0 = (unsigned)(r0 * 1024 + (((kk * 32 + kbb) * 2) ^ ((r0 & 7) << 4)));
      unsigned o1 = (unsigned)(r1 * 1024 + (((kk * 32 + kbb) * 2) ^ ((r0 & 7) << 4)));
      bf16x8 a0 = *(const bf16x8*)((const char*)lstage + o0);
      bf16x8 a1 = *(const bf16x8*)((const char*)lstage + o1);
      acc0 = __builtin_amdgcn_mfma_f32_16x16x32_bf16(a0, wx[kk], acc0, 0, 0, 0);
      acc1 = __builtin_amdgcn_mfma_f32_16x16x32_bf16(a1, wx[kk], acc1, 0, 0, 0);
    }
  }

  for (int t = 0; t < TS; ++t) {
    const int tsrc = dir ? (TS - 1 - t) : t;
    if (t > 0) {
      if (wv == 0) {
        const int target = t;
        for (;;) {
          int v = (lane < 32)
              ? __hip_atomic_load(flp + lane * FLAG_STRIDE, __ATOMIC_RELAXED,
                                  __HIP_MEMORY_SCOPE_AGENT)
              : 0x7fffffff;
          if (__all(v >= target)) break;
          __builtin_amdgcn_s_sleep(2);
        }
      }
      __syncthreads();
    }
    unsigned int* hu = (t == 0)
        ? (unsigned int*)hI
        : (unsigned int*)(out + (size_t)(tsrc + (dir ? 1 : -1)) * BATCH * HID);
    unsigned int hreg[32];
#pragma unroll
    for (int it = 0; it < 32; ++it) hreg[it] = ald(hu + it * 256 + tid);
    __syncthreads();
#pragma unroll
    for (int it = 0; it < 32; ++it) {
      int dw = it * 256 + tid;
      int row = dw >> 8;
      unsigned lb = (unsigned)(row * 1024 +
                               (((dw & 252) << 2) ^ ((row & 7) << 4)) +
                               ((dw & 3) << 2));
      *(unsigned int*)((char*)lstage + lb) = hreg[it];
    }
    __syncthreads();
#pragma unroll
    for (int kk = 0; kk < 16; ++kk) {
      unsigned o0 = (unsigned)(r0 * 1024 + (((kk * 32 + kbb) * 2) ^ ((r0 & 7) << 4)));
      unsigned o1 = (unsigned)(r1 * 1024 + (((kk * 32 + kbb) * 2) ^ ((r0 & 7) << 4)));
      bf16x8 a0 = *(const bf16x8*)((const char*)lstage + o0);
      bf16x8 a1 = *(const bf16x8*)((const char*)lstage + o1);
      acc0 = __builtin_amdgcn_mfma_f32_16x16x32_bf16(a0, wh[kk], acc0, 0, 0, 0);
      acc1 = __builtin_amdgcn_mfma_f32_16x16x32_bf16(a1, wh[kk], acc1, 0, 0, 0);
    }
#pragma unroll
    for (int r = 0; r < 4; ++r) {
      int brow = (lane >> 4) * 4 + r;
      gbuf[brow * 68 + nloc] = acc0[r] + bv;
      gbuf[(16 + brow) * 68 + nloc] = acc1[r] + bv;
    }
    __syncthreads();
    {
      float gi0 = gbuf[gb * 68 + gj],      gf0 = gbuf[gb * 68 + 16 + gj];
      float gg0 = gbuf[gb * 68 + 32 + gj], go0 = gbuf[gb * 68 + 48 + gj];
      float gi1 = gbuf[gb * 68 + gj + 1],      gf1 = gbuf[gb * 68 + 16 + gj + 1];
      float gg1 = gbuf[gb * 68 + 32 + gj + 1], go1 = gbuf[gb * 68 + 48 + gj + 1];
      float cn0 = sigm(gf0) * c0 + sigm(gi0) * tanhf(gg0); c0 = cn0;
      float cn1 = sigm(gf1) * c1 + sigm(gi1) * tanhf(gg1); c1 = cn1;
      unsigned int hv = (unsigned int)f2b(sigm(go0) * tanhf(cn0)) |
                        ((unsigned int)f2b(sigm(go1) * tanhf(cn1)) << 16);
      ast((unsigned int*)out + (size_t)tsrc * (BATCH * HID / 2) +
              gb * (HID / 2) + blk16 * 8 + (tid & 7), hv);
    }
    if (t + 1 < TS) {
      __syncthreads();
      if (wv == 0 && lane == 0)
        __hip_atomic_store(flp + blk16 * FLAG_STRIDE, t + 1,
                           __ATOMIC_RELAXED, __HIP_MEMORY_SCOPE_AGENT);
      const int tn = dir ? (TS - 2 - t) : (t + 1);
#pragma unroll
      for (int it = 0; it < 8; ++it) {
        int ci = it * 256 + tid;
        int row = ci >> 6;
        int k8 = (ci & 63) << 3;
        uint4 v = *(const uint4*)(artb + (size_t)tn * BATCH * HID +
                                  (size_t)row * HID + k8);
        unsigned off = (unsigned)(row * 1024 + ((k8 * 2) ^ ((row & 7) << 4)));
        *(uint4*)((char*)lstage + off) = v;
      }
      __syncthreads();
      acc0 = (f32x4){0.f, 0.f, 0.f, 0.f};
      acc1 = (f32x4){0.f, 0.f, 0.f, 0.f};
#pragma unroll
      for (int kk = 0; kk < 16; ++kk) {
        unsigned o0 = (unsigned)(r0 * 1024 + (((kk * 32 + kbb) * 2) ^ ((r0 & 7) << 4)));
        unsigned o1 = (unsigned)(r1 * 1024 + (((kk * 32 + kbb) * 2) ^ ((r0 & 7) << 4)));
        bf16x8 a0 = *(const bf16x8*)((const char*)lstage + o0);
        bf16x8 a1 = *(const bf16x8*)((const char*)lstage + o1);
        acc0 = __builtin_amdgcn_mfma_f32_16x16x32_bf16(a0, wx[kk], acc0, 0, 0, 0);
        acc1 = __builtin_amdgcn_mfma_f32_16x16x32_bf16(a1, wx[kk], acc1, 0, 0, 0);
      }
    }
  }
  cg[gb * HID + blk16 * 16 + gj] = c0;
  cg[gb * HID + blk16 * 16 + gj + 1] = c1;
}

// ---------------------------------------------------------------------------
// Persistent fused decoder R16: 4 barriers/step.
// P1 cell (gates = ge[i] + z@Wfold + h@Whh; weights in VGPRs) | P2 q + z-h
// | P3 flash | P4 z-ctx + tanh -> zb bf16 | (b4) | P5 out (no barrier).
// ---------------------------------------------------------------------------
__global__ __launch_bounds__(512, 1) void dec_all_k(
    unsigned short* __restrict__ hd0, unsigned short* __restrict__ hd1,
    const float* __restrict__ cdec,
    const unsigned short* __restrict__ pkZ,   // Wfold B-frags (gate layout)
    const unsigned short* __restrict__ pkH,
    const void* __restrict__ dbias,
    const float* __restrict__ geb,            // [64][2048] f32
    const unsigned short* __restrict__ att,
    const unsigned short* __restrict__ pkq,
    const unsigned short* __restrict__ pkw1,
    const unsigned short* __restrict__ b1p,
    const unsigned short* __restrict__ pkw2,
    const int* __restrict__ lens,
    void* __restrict__ dout,
    float* __restrict__ qg,
    unsigned int* __restrict__ ctxb,
    unsigned int* __restrict__ zb,            // [32][256] dwords (bf16 pairs)
    int* __restrict__ flags, const int* dtf) {
  const int f32f = dtf[0];
  const int blk = blockIdx.x;
  const int tid = threadIdx.x;
  const int lane = tid & 63;
  const int wv = tid >> 6;
  __shared__ __align__(16) char smem[49152];

  const int gb = tid >> 3;
  const int gj = (tid & 7) * 2;
  const int r0 = lane & 15;
  const int r1 = 16 + r0;
  const int kbb = (lane >> 4) * 8;
  const int nloc = wv * 16 + (lane & 15);
  float c0 = 0.f, c1 = 0.f, bv = 0.f;
  int orow = 0;
  bf16x8 cwz[16], cwh[16];
  if (tid < 256) {
    c0 = cdec[gb * HID + blk * 16 + gj];
    c1 = cdec[gb * HID + blk * 16 + gj + 1];
    orow = (nloc >> 4) * HID + blk * 16 + (nloc & 15);
    bv = ldf(dbias, orow, f32f);
    const int tile = blk * 4 + wv;
    const unsigned short* pz = pkZ + ((size_t)tile * 16 * 64 + lane) * 8;
    const unsigned short* ph = pkH + ((size_t)tile * 16 * 64 + lane) * 8;
#pragma unroll
    for (int kk = 0; kk < 16; ++kk) {
      cwz[kk] = *(const bf16x8*)(pz + (size_t)kk * 64 * 8);
      cwh[kk] = *(const bf16x8*)(ph + (size_t)kk * 64 * 8);
    }
  }

  int ep = 0;
  auto gbar = [&]() {
    __syncthreads();
    ++ep;
    if (wv == 0) {
      if (lane == 0)
        __hip_atomic_store(flags + blk * FLAG_STRIDE, ep, __ATOMIC_RELAXED,
                           __HIP_MEMORY_SCOPE_AGENT);
      for (;;) {
        int v = (lane < 32)
            ? __hip_atomic_load(flags + lane * FLAG_STRIDE, __ATOMIC_RELAXED,
                                __HIP_MEMORY_SCOPE_AGENT)
            : 0x7fffffff;
        if (__all(v >= ep)) break;
        __builtin_amdgcn_s_sleep(2);
      }
    }
    __syncthreads();
  };

  auto stage8k = [&](const unsigned int* src, unsigned short* lstage) {
    unsigned int rg[16];
#pragma unroll
    for (int it = 0; it < 16; ++it) rg[it] = ald(src + it * 512 + tid);
#pragma unroll
    for (int it = 0; it < 16; ++it) {
      int dw = it * 512 + tid;
      int row = dw >> 8;
      unsigned lb = (unsigned)(row * 1024 +
                               (((dw & 252) << 2) ^ ((row & 7) << 4)) +
                               ((dw & 3) << 2));
      *(unsigned int*)((char*)lstage + lb) = rg[it];
    }
  };

  auto afrag = [&](const unsigned short* lstage, int kk, bf16x8& a0, bf16x8& a1) {
    unsigned o0 = (unsigned)(r0 * 1024 + (((kk * 32 + kbb) * 2) ^ ((r0 & 7) << 4)));
    unsigned o1 = (unsigned)(r1 * 1024 + (((kk * 32 + kbb) * 2) ^ ((r0 & 7) << 4)));
    a0 = *(const bf16x8*)((const char*)lstage + o0);
    a1 = *(const bf16x8*)((const char*)lstage + o1);
  };

  for (int i = 0; i < TG; ++i) {
    unsigned short* hin = (i & 1) ? hd1 : hd0;
    unsigned short* hout = (i & 1) ? hd0 : hd1;
    f32x4 zacc0 = {0.f, 0.f, 0.f, 0.f};   // z partials carried P2 -> P4
    f32x4 zacc1 = {0.f, 0.f, 0.f, 0.f};

    // ===== P1: cell — gates = ge[i] + z_prev@Wfold + h@Whh (waves 0-3) =====
    {
      unsigned short* lstage = (unsigned short*)smem;
      float* gbuf = (float*)(smem + 32768);
      f32x4 acc0 = {0.f, 0.f, 0.f, 0.f};
      f32x4 acc1 = {0.f, 0.f, 0.f, 0.f};
      unsigned int hreg[32];
      if (tid < 256) {
        unsigned int zreg[32];
#pragma unroll
        for (int it = 0; it < 32; ++it) zreg[it] = ald(zb + it * 256 + tid);
#pragma unroll
        for (int it = 0; it < 32; ++it) {
          int dw = it * 256 + tid;
          int row = dw >> 8;
          unsigned lb = (unsigned)(row * 1024 +
                                   (((dw & 252) << 2) ^ ((row & 7) << 4)) +
                                   ((dw & 3) << 2));
          *(unsigned int*)((char*)lstage + lb) = zreg[it];
        }
      }
      __syncthreads();
      if (tid < 256) {
        const unsigned int* hu = (const unsigned int*)hin;
#pragma unroll
        for (int it = 0; it < 32; ++it) hreg[it] = ald(hu + it * 256 + tid);
#pragma unroll
        for (int kk = 0; kk < 16; ++kk) {
          bf16x8 a0, a1;
          afrag(lstage, kk, a0, a1);
          acc0 = __builtin_amdgcn_mfma_f32_16x16x32_bf16(a0, cwz[kk], acc0, 0, 0, 0);
          acc1 = __builtin_amdgcn_mfma_f32_16x16x32_bf16(a1, cwz[kk], acc1, 0, 0, 0);
        }
      }
      __syncthreads();
      if (tid < 256) {
#pragma unroll
        for (int it = 0; it < 32; ++it) {
          int dw = it * 256 + tid;
          int row = dw >> 8;
          unsigned lb = (unsigned)(row * 1024 +
                                   (((dw & 252) << 2) ^ ((row & 7) << 4)) +
                                   ((dw & 3) << 2));
          *(unsigned int*)((char*)lstage + lb) = hreg[it];
        }
      }
      __syncthreads();
      if (tid < 256) {
#pragma unroll
        for (int kk = 0; kk < 16; ++kk) {
          bf16x8 a0, a1;
          afrag(lstage, kk, a0, a1);
          acc0 = __builtin_amdgcn_mfma_f32_16x16x32_bf16(a0, cwh[kk], acc0, 0, 0, 0);
          acc1 = __builtin_amdgcn_mfma_f32_16x16x32_bf16(a1, cwh[kk], acc1, 0, 0, 0);
        }
        float gev = geb[(size_t)i * 2048 + orow];
#pragma unroll
        for (int r = 0; r < 4; ++r) {
          int brow = (lane >> 4) * 4 + r;
          gbuf[brow * 68 + nloc] = acc0[r] + bv + gev;
          gbuf[(16 + brow) * 68 + nloc] = acc1[r] + bv + gev;
        }
      }
      __syncthreads();
      if (tid < 256) {
        float gi0 = gbuf[gb * 68 + gj],      gf0 = gbuf[gb * 68 + 16 + gj];
        float gg0 = gbuf[gb * 68 + 32 + gj], go0 = gbuf[gb * 68 + 48 + gj];
        float gi1 = gbuf[gb * 68 + gj + 1],      gf1 = gbuf[gb * 68 + 16 + gj + 1];
        float gg1 = gbuf[gb * 68 + 32 + gj + 1], go1 = gbuf[gb * 68 + 48 + gj + 1];
        float cn0 = sigm(gf0) * c0 + sigm(gi0) * tanhf(gg0); c0 = cn0;
        float cn1 = sigm(gf1) * c1 + sigm(gi1) * tanhf(gg1); c1 = cn1;
        float hn0 = sigm(go0) * tanhf(cn0);
        float hn1 = sigm(go1) * tanhf(cn1);
        ast((unsigned int*)hout + gb * (HID / 2) + blk * 8 + (tid & 7),
            (unsigned int)f2b(hn0) | ((unsigned int)f2b(hn1) << 16));
        size_t e0 = ((size_t)gb * TG + i) * HID + blk * 16 + gj;
        stf(dout, OFF_H + e0, hn0, f32f);
        stf(dout, OFF_H + e0 + 1, hn1, f32f);
        stf(dout, OFF_C + e0, cn0, f32f);
        stf(dout, OFF_C + e0 + 1, cn1, f32f);
      }
    }
    gbar();   // b1: h ready

    // ====== P2: q = h@wq AND z-h-half = h@W1[:512] (partials in regs) ======
    {
      unsigned short* lstage = (unsigned short*)smem;
      float* part = (float*)(smem + 32768);
      stage8k((const unsigned int*)hout, lstage);
      __syncthreads();
      f32x4 acc0 = {0.f, 0.f, 0.f, 0.f};
      f32x4 acc1 = {0.f, 0.f, 0.f, 0.f};
#pragma unroll
      for (int j = 0; j < 2; ++j) {
        int kk = wv * 2 + j;
        bf16x8 a0, a1;
        afrag(lstage, kk, a0, a1);
        bf16x8 bq = *(const bf16x8*)(pkq + ((size_t)(blk * 16 + kk) * 64 + lane) * 8);
        acc0 = __builtin_amdgcn_mfma_f32_16x16x32_bf16(a0, bq, acc0, 0, 0, 0);
        acc1 = __builtin_amdgcn_mfma_f32_16x16x32_bf16(a1, bq, acc1, 0, 0, 0);
        bf16x8 bw = *(const bf16x8*)(pkw1 + ((size_t)(blk * 32 + kk) * 64 + lane) * 8);
        zacc0 = __builtin_amdgcn_mfma_f32_16x16x32_bf16(a0, bw, zacc0, 0, 0, 0);
        zacc1 = __builtin_amdgcn_mfma_f32_16x16x32_bf16(a1, bw, zacc1, 0, 0, 0);
      }
#pragma unroll
      for (int r = 0; r < 4; ++r) {
        int m0 = (lane >> 4) * 4 + r;
        part[wv * 512 + m0 * 16 + (lane & 15)] = acc0[r];
        part[wv * 512 + (m0 + 16) * 16 + (lane & 15)] = acc1[r];
      }
      __syncthreads();
      {
        float s = 0.f;
#pragma unroll
        for (int w = 0; w < 8; ++w) s += part[w * 512 + tid];
        int bb2 = tid >> 4, cl = tid & 15;
        astf(qg + (size_t)bb2 * HID + blk * 16 + cl, s);
      }
    }
    gbar();   // b2: q ready

    // ============ P3: flash score+ctx, 4-row unroll (block = batch) ========
    {
      const int b = blk;
      const int len = lens[b];
      float* cred = (float*)smem;
      float* mwl  = (float*)(smem + 16384);
      float* lwl  = (float*)(smem + 16448);
      float* qf   = (float*)(smem + 16512);
      float* ctxf = (float*)(smem + 18560);
      qf[tid] = aldf(qg + (size_t)b * HID + tid);
      __syncthreads();
      float qv[8];
#pragma unroll
      for (int e = 0; e < 8; ++e) qv[e] = qf[lane * 8 + e];
      float m = -1e30f, l = 0.f;
      float ca[8] = {0.f, 0.f, 0.f, 0.f, 0.f, 0.f, 0.f, 0.f};
      const unsigned short* ab = att + ((size_t)b * TS + wv * 128) * HID + lane * 8;
      for (int tt = 0; tt < 128; tt += 4) {
        int t = wv * 128 + tt;
        bf16x8 rr0 = *(const bf16x8*)(ab + (size_t)(tt + 0) * HID);
        bf16x8 rr1 = *(const bf16x8*)(ab + (size_t)(tt + 1) * HID);
        bf16x8 rr2 = *(const bf16x8*)(ab + (size_t)(tt + 2) * HID);
        bf16x8 rr3 = *(const bf16x8*)(ab + (size_t)(tt + 3) * HID);
        float s0 = 0.f, s1 = 0.f, s2 = 0.f, s3 = 0.f;
#pragma unroll
        for (int e = 0; e < 8; ++e) {
          float q = qv[e];
          s0 += q * b2f(((const unsigned short*)&rr0)[e]);
          s1 += q * b2f(((const unsigned short*)&rr1)[e]);
          s2 += q * b2f(((const unsigned short*)&rr2)[e]);
          s3 += q * b2f(((const unsigned short*)&rr3)[e]);
        }
        for (int o = 32; o; o >>= 1) {
          s0 += __shfl_xor(s0, o, 64); s1 += __shfl_xor(s1, o, 64);
          s2 += __shfl_xor(s2, o, 64); s3 += __shfl_xor(s3, o, 64);
        }
        bool v0 = (t < len), v1 = (t + 1 < len), v2 = (t + 2 < len), v3 = (t + 3 < len);
        float smax = fmaxf(fmaxf(v0 ? s0 : -1e30f, v1 ? s1 : -1e30f),
                           fmaxf(v2 ? s2 : -1e30f, v3 ? s3 : -1e30f));
        if (smax > m) {
          float sc2 = expf(m - smax);
          l *= sc2;
#pragma unroll
          for (int e = 0; e < 8; ++e) ca[e] *= sc2;
          m = smax;
        }
        if (v0) { float p = expf(s0 - m); l += p;
#pragma unroll
          for (int e = 0; e < 8; ++e) ca[e] += p * b2f(((const unsigned short*)&rr0)[e]); }
        if (v1) { float p = expf(s1 - m); l += p;
#pragma unroll
          for (int e = 0; e < 8; ++e) ca[e] += p * b2f(((const unsigned short*)&rr1)[e]); }
        if (v2) { float p = expf(s2 - m); l += p;
#pragma unroll
          for (int e = 0; e < 8; ++e) ca[e] += p * b2f(((const unsigned short*)&rr2)[e]); }
        if (v3) { float p = expf(s3 - m); l += p;
#pragma unroll
          for (int e = 0; e < 8; ++e) ca[e] += p * b2f(((const unsigned short*)&rr3)[e]); }
      }
#pragma unroll
      for (int e = 0; e < 8; ++e) cred[wv * 512 + lane * 8 + e] = ca[e];
      if (lane == 0) { mwl[wv] = m; lwl[wv] = l; }
      __syncthreads();
      {
        float M = -1e30f;
#pragma unroll
        for (int w = 0; w < 8; ++w) M = fmaxf(M, mwl[w]);
        float L = 0.f, s = 0.f;
#pragma unroll
        for (int w = 0; w < 8; ++w) {
          float sc2 = expf(mwl[w] - M);
          L += lwl[w] * sc2;
          s += cred[w * 512 + tid] * sc2;
        }
        ctxf[tid] = s / L;
      }
      __syncthreads();
      if (tid < 256) {
        unsigned int d = (unsigned int)f2b(ctxf[2 * tid]) |
                         ((unsigned int)f2b(ctxf[2 * tid + 1]) << 16);
        ast(ctxb + b * 256 + tid, d);
      }
    }
    gbar();   // b3: ctx ready

    // ====== P4: z ctx-half adds onto carried partials; tanh -> zb bf16 =====
    {
      unsigned short* lstage = (unsigned short*)smem;
      float* part = (float*)(smem + 32768);
      stage8k(ctxb, lstage);
      __syncthreads();
#pragma unroll
      for (int j = 0; j < 2; ++j) {
        int kkl = wv * 2 + j;
        bf16x8 a0, a1;
        afrag(lstage, kkl, a0, a1);
        bf16x8 bb = *(const bf16x8*)(pkw1 + ((size_t)(blk * 32 + 16 + kkl) * 64 + lane) * 8);
        zacc0 = __builtin_amdgcn_mfma_f32_16x16x32_bf16(a0, bb, zacc0, 0, 0, 0);
        zacc1 = __builtin_amdgcn_mfma_f32_16x16x32_bf16(a1, bb, zacc1, 0, 0, 0);
      }
      __syncthreads();
#pragma unroll
      for (int r = 0; r < 4; ++r) {
        int m0 = (lane >> 4) * 4 + r;
        part[wv * 512 + m0 * 16 + (lane & 15)] = zacc0[r];
        part[wv * 512 + (m0 + 16) * 16 + (lane & 15)] = zacc1[r];
      }
      __syncthreads();
      {
        float s = 0.f;
#pragma unroll
        for (int w = 0; w < 8; ++w) s += part[w * 512 + tid];
        int bb2 = tid >> 4, cl = tid & 15;
        int col = blk * 16 + cl;
        float zv = tanhf(b2f(b1p[col]) + s);
        unsigned short me = f2b(zv);
        int other = __shfl_xor((int)me, 1);
        if (!(tid & 1))
          ast(zb + bb2 * 256 + (col >> 1),
              (unsigned int)me | ((unsigned int)(other & 0xffff) << 16));
      }
    }
    gbar();   // b4: z ready (also gates next P1)

    // ====== P5: out = z @ W2 (blocks 0..15), NO trailing barrier ===========
    if (blk < 16) {
      unsigned short* lstage = (unsigned short*)smem;
      float* part = (float*)(smem + 32768);
      stage8k(zb, lstage);
      __syncthreads();
      f32x4 acc0 = {0.f, 0.f, 0.f, 0.f};
      f32x4 acc1 = {0.f, 0.f, 0.f, 0.f};
#pragma unroll
      for (int j = 0; j < 2; ++j) {
        int kk = wv * 2 + j;
        bf16x8 a0, a1;
        afrag(lstage, kk, a0, a1);
        bf16x8 bb = *(const bf16x8*)(pkw2 + ((size_t)(blk * 16 + kk) * 64 + lane) * 8);
        acc0 = __builtin_amdgcn_mfma_f32_16x16x32_bf16(a0, bb, acc0, 0, 0, 0);
        acc1 = __builtin_amdgcn_mfma_f32_16x16x32_bf16(a1, bb, acc1, 0, 0, 0);
      }
#pragma unroll
      for (int r = 0; r < 4; ++r) {
        int m0 = (lane >> 4) * 4 + r;
        part[wv * 512 + m0 * 16 + (lane & 15)] = acc0[r];
        part[wv * 512 + (m0 + 16) * 16 + (lane & 15)] = acc1[r];
      }
      __syncthreads();
      {
        float s = 0.f;
#pragma unroll
        for (int w = 0; w < 8; ++w) s += part[w * 512 + tid];
        int bb2 = tid >> 4, cl = tid & 15;
        int col = blk * 16 + cl;
        stf(dout, ((size_t)bb2 * TG + i) * EDIM + col, s, f32f);
      }
      __syncthreads();   // lstage reused by next P1 (block-local, safe)
    }
  }
}

__global__ __launch_bounds__(256) void attn_mm_k(
    const unsigned short* __restrict__ outF, const unsigned short* __restrict__ outB,
    const unsigned short* __restrict__ pkwm, unsigned short* __restrict__ att) {
  __shared__ char ldsA[4 * 1040];
  int bid = blockIdx.x;
  int bn = bid & 7, bm = bid >> 3;
  int tid = threadIdx.x, lane = tid & 63, wv = tid >> 6;
  int r0 = bm * 64;
  f32x4 acc[2][2] = {};
  int srow = tid >> 2, skb = tid & 3;
  int mt0 = (wv & 1) * 2, nt0 = (wv >> 1) * 2;
  for (int kk = 0; kk < 32; ++kk) {
    int kg = kk * 32 + skb * 8;
    const unsigned short* src = (kg < HID)
        ? (outF + (size_t)(r0 + srow) * HID + kg)
        : (outB + (size_t)(r0 + srow) * HID + (kg - HID));
    uint4 v = *(const uint4*)src;
    __syncthreads();
    *(uint4*)(ldsA + skb * 1040 + srow * 16) = v;
    __syncthreads();
    bf16x8 a[2], bb[2];
#pragma unroll
    for (int mi = 0; mi < 2; ++mi) {
      int rl = (mt0 + mi) * 16 + (lane & 15);
      a[mi] = *(const bf16x8*)(ldsA + (lane >> 4) * 1040 + rl * 16);
    }
#pragma unroll
    for (int nj = 0; nj < 2; ++nj) {
      int ntg = bn * 4 + nt0 + nj;
      bb[nj] = *(const bf16x8*)(pkwm + ((size_t)(ntg * 32 + kk) * 64 + lane) * 8);
    }
#pragma unroll
    for (int mi = 0; mi < 2; ++mi)
#pragma unroll
      for (int nj = 0; nj < 2; ++nj)
        acc[mi][nj] = __builtin_amdgcn_mfma_f32_16x16x32_bf16(a[mi], bb[nj], acc[mi][nj], 0, 0, 0);
  }
#pragma unroll
  for (int mi = 0; mi < 2; ++mi)
#pragma unroll
    for (int nj = 0; nj < 2; ++nj)
#pragma unroll
      for (int r = 0; r < 4; ++r) {
        int row = r0 + (mt0 + mi) * 16 + (lane >> 4) * 4 + r;
        int t = row >> 5, b = row & 31;
        int h = bn * 64 + (nt0 + nj) * 16 + (lane & 15);
        att[((size_t)b * TS + t) * HID + h] = f2b(acc[mi][nj][r]);
      }
}

__global__ void init_states_k(const void* __restrict__ ih, const void* __restrict__ ic,
                              unsigned short* hIF, unsigned short* hIB,
                              float* cF, float* cB, int* bar, const int* dtf) {
  int f32f = dtf[0];
  int g = blockIdx.x * 256 + threadIdx.x;
  if (g < (64 + 32) * FLAG_STRIDE)
    __hip_atomic_store(bar + g, 0, __ATOMIC_RELAXED, __HIP_MEMORY_SCOPE_AGENT);
  int b = g >> 9, j = g & 511;
  hIF[b * HID + j] = f2b(ldf(ih, j, f32f));
  hIB[b * HID + j] = f2b(ldf(ih, HID + j, f32f));
  cF[b * HID + j] = ldf(ic, j, f32f);
  cB[b * HID + j] = ldf(ic, HID + j, f32f);
}

__global__ void seqmean_k(const unsigned short* __restrict__ att,
                          const int* __restrict__ lens, float* __restrict__ sm) {
  int b = blockIdx.x, tid = threadIdx.x;
  int len = lens[b];
  float a0 = 0.f, a1 = 0.f;
  for (int t = 0; t < len; ++t) {
    const unsigned short* row = att + ((size_t)b * TS + t) * HID;
    a0 += b2f(row[tid]);
    a1 += b2f(row[tid + 256]);
  }
  float fl = (float)len;
  sm[b * HID + tid] = a0 / fl;
  sm[b * HID + tid + 256] = a1 / fl;
}

__global__ void mv_bb_k(const unsigned short* __restrict__ A1,
                        const unsigned short* __restrict__ A2,
                        const void* __restrict__ W, unsigned short* __restrict__ o,
                        const int* dtf) {
  int f32f = dtf[0];
  int g = blockIdx.x * 256 + threadIdx.x;
  int b = g >> 9, n = g & 511;
  float acc = 0.f;
  for (int k = 0; k < HID; ++k) acc += b2f(A1[b * HID + k]) * ldf(W, (size_t)k * HID + n, f32f);
  for (int k = 0; k < HID; ++k) acc += b2f(A2[b * HID + k]) * ldf(W, (size_t)(HID + k) * HID + n, f32f);
  o[b * HID + n] = f2b(acc);
}

__global__ void mv_ff_k(const float* __restrict__ A1, const float* __restrict__ A2,
                        const void* __restrict__ W, float* __restrict__ o, const int* dtf) {
  int f32f = dtf[0];
  int g = blockIdx.x * 256 + threadIdx.x;
  int b = g >> 9, n = g & 511;
  float acc = 0.f;
  for (int k = 0; k < HID; ++k) acc += A1[b * HID + k] * ldf(W, (size_t)k * HID + n, f32f);
  for (int k = 0; k < HID; ++k) acc += A2[b * HID + k] * ldf(W, (size_t)(HID + k) * HID + n, f32f);
  o[b * HID + n] = acc;
}

__global__ void proj1_k(const unsigned short* __restrict__ A1, const float* __restrict__ A2,
                        const void* __restrict__ W1p, const void* __restrict__ b1p,
                        unsigned short* __restrict__ z, const int* dtf) {
  int f32f = dtf[0];
  int g = blockIdx.x * 256 + threadIdx.x;
  int b = g >> 9, n = g & 511;
  float acc = ldf(b1p, n, f32f);
  for (int k = 0; k < HID; ++k) acc += b2f(A1[b * HID + k]) * ldf(W1p, (size_t)k * HID + n, f32f);
  for (int k = 0; k < HID; ++k) acc += A2[b * HID + k] * ldf(W1p, (size_t)(HID + k) * HID + n, f32f);
  z[b * HID + n] = f2b(tanhf(acc));
}

extern "C" void kernel_launch(void* const* d_in, const int* in_sizes, int n_in,
                              void* d_out, int out_size, void* d_ws, size_t ws_size,
                              hipStream_t stream) {
  (void)in_sizes; (void)n_in;
  const void* article = d_in[0];
  const int* art_lens = (const int*)d_in[1];
  const void* emb  = d_in[3];
  const void* eWxf = d_in[4]; const void* eWhf = d_in[5]; const void* ebf = d_in[6];
  const void* eWxb = d_in[7]; const void* eWhb = d_in[8]; const void* ebb = d_in[9];
  const void* initH = d_in[10]; const void* initC = d_in[11];
  const void* dhW = d_in[12]; const void* dcW = d_in[13];
  const void* wm = d_in[14]; const void* wq = d_in[15];
  const void* W1 = d_in[16]; const void* b1 = d_in[17]; const void* W2 = d_in[18];
  const void* dWx = d_in[19]; const void* dWh = d_in[20]; const void* db = d_in[21];

  char* ws = (char*)d_ws;
  size_t off = 0;
  auto take = [&](size_t bytes) -> char* {
    char* p = ws + off;
    off = (off + bytes + 255) & ~(size_t)255;
    return p;
  };
  int* dtf = (int*)take(4);
  int* bar = (int*)take((64 + 32) * FLAG_STRIDE * 4);
  unsigned short* pk_exf = (unsigned short*)take((size_t)GD * HID * 2);
  unsigned short* pk_ehf = (unsigned short*)take((size_t)GD * HID * 2);
  unsigned short* pk_exb = (unsigned short*)take((size_t)GD * HID * 2);
  unsigned short* pk_ehb = (unsigned short*)take((size_t)GD * HID * 2);
  unsigned short* pk_fold = (unsigned short*)take((size_t)GD * HID * 2);
  unsigned short* pk_dh  = (unsigned short*)take((size_t)GD * HID * 2);
  unsigned short* pk_wm  = (unsigned short*)take((size_t)1024 * HID * 2);
  unsigned short* pkq  = (unsigned short*)take((size_t)512 * 512 * 2);
  unsigned short* pkw1 = (unsigned short*)take((size_t)1024 * 512 * 2);
  unsigned short* b1p  = (unsigned short*)take((size_t)HID * 2);
  unsigned short* pkw2 = (unsigned short*)take((size_t)512 * 256 * 2);
  float* wfoldf = (float*)take((size_t)GD * HID * 4);
  float* geb = (float*)take((size_t)TG * GD * 4);
  unsigned short* outF = (unsigned short*)take((size_t)TS * BATCH * HID * 2);
  unsigned short* outB = (unsigned short*)take((size_t)TS * BATCH * HID * 2);
  unsigned short* att  = (unsigned short*)take((size_t)BATCH * TS * HID * 2);
  unsigned short* hIF  = (unsigned short*)take((size_t)BATCH * HID * 2);
  unsigned short* hIB  = (unsigned short*)take((size_t)BATCH * HID * 2);
  float* cF = (float*)take((size_t)BATCH * HID * 4);
  float* cB = (float*)take((size_t)BATCH * HID * 4);
  unsigned short* hd0 = (unsigned short*)take((size_t)BATCH * HID * 2);
  unsigned short* hd1 = (unsigned short*)take((size_t)BATCH * HID * 2);
  float* cdec = (float*)take((size_t)BATCH * HID * 4);
  unsigned short* zbuf = (unsigned short*)take((size_t)BATCH * HID * 2);
  float* qg = (float*)take((size_t)BATCH * HID * 4);
  unsigned int* ctxb = (unsigned int*)take((size_t)BATCH * 256 * 4);
  float* sm = (float*)take((size_t)BATCH * HID * 4);

  if (off > ws_size) {
    fill_sig_k<<<(out_size + 255) / 256, 256, 0, stream>>>((unsigned short*)d_out, out_size);
    return;
  }

  unsigned short* artb = att;   // alias: article-bf16 live only during encoding

  detect_k<<<1, 256, 0, stream>>>(article, dtf);
  pack_gate_k<<<512, 256, 0, stream>>>(eWxf, pk_exf, dtf);
  pack_gate_k<<<512, 256, 0, stream>>>(eWhf, pk_ehf, dtf);
  pack_gate_k<<<512, 256, 0, stream>>>(eWxb, pk_exb, dtf);
  pack_gate_k<<<512, 256, 0, stream>>>(eWhb, pk_ehb, dtf);
  pack_gate_k<<<512, 256, 0, stream>>>(dWh, pk_dh, dtf);
  fold_w_k<<<2048, 256, 0, stream>>>(dWx, W2, wfoldf, dtf);
  ge_k<<<512, 256, 0, stream>>>(emb, dWx, geb, dtf);
  pack_gate_f32_k<<<512, 256, 0, stream>>>(wfoldf, pk_fold);
  pack_wm_k<<<256, 256, 0, stream>>>(wm, pk_wm, dtf);
  pack_bn_k<<<128, 256, 0, stream>>>(wq, pkq, 512, 512, 32 * 16 * 64, dtf);
  pack_bn_k<<<256, 256, 0, stream>>>(W1, pkw1, 1024, 512, 32 * 32 * 64, dtf);
  pack_bn_k<<<64, 256, 0, stream>>>(W2, pkw2, 512, 256, 16 * 16 * 64, dtf);
  pack_bf16_k<<<2, 256, 0, stream>>>(b1, b1p, HID, dtf);
  pack_bf16_k<<<65536, 256, 0, stream>>>(article, artb, TS * BATCH * HID, dtf);
  init_states_k<<<64, 256, 0, stream>>>(initH, initC, hIF, hIB, cF, cB, bar, dtf);

  enc_all_k<<<64, 256, 0, stream>>>(artb, outF, outB, hIF, hIB, cF, cB,
                                    pk_exf, pk_ehf, pk_exb, pk_ehb, ebf, ebb,
                                    bar, dtf);

  attn_mm_k<<<4096, 256, 0, stream>>>(outF, outB, pk_wm, att);
  seqmean_k<<<32, 256, 0, stream>>>(att, art_lens, sm);
  mv_bb_k<<<64, 256, 0, stream>>>(outF + (size_t)(TS - 1) * BATCH * HID, outB, dhW, hd0, dtf);
  mv_ff_k<<<64, 256, 0, stream>>>(cF, cB, dcW, cdec, dtf);
  proj1_k<<<64, 256, 0, stream>>>(hd0, sm, W1, b1, zbuf, dtf);
  // z_{-1} = proj1 output; zbuf's bf16 layout IS the zb dword layout.

  dec_all_k<<<32, 512, 0, stream>>>(hd0, hd1, cdec, pk_fold, pk_dh, db, geb,
                                    att, pkq, pkw1, b1p, pkw2, art_lens,
                                    d_out, qg, ctxb, (unsigned int*)zbuf,
                                    bar + 64 * FLAG_STRIDE, dtf);
}

// Round 17
// 8756.607 us; speedup vs baseline: 1.1287x; 1.1287x over previous
//
#include <hip/hip_runtime.h>

// Seq2Seq forward. R17: one-shot-kernel cleanup — fold computed via W2
// transpose + coalesced streaming (R16's fold_w_k line-thrashed ~0.5ms),
// seqmean given 8-deep load ILP (was a 1024-long serial latency chain).
// Encoder (R14 pipeline) and decoder (R16 folded-W2, 4 barriers) untouched.

#define DI __device__ __forceinline__

constexpr int BATCH = 32;
constexpr int TS = 1024;
constexpr int TG = 64;
constexpr int HID = 512;
constexpr int GD = 2048;
constexpr int EDIM = 256;
constexpr int SPECIAL = 4;
constexpr size_t OFF_H = (size_t)BATCH * TG * EDIM;
constexpr size_t OFF_C = OFF_H + (size_t)BATCH * TG * HID;
constexpr int FLAG_STRIDE = 16;   // dwords (64B) per flag

typedef __attribute__((ext_vector_type(8))) short bf16x8;
typedef __attribute__((ext_vector_type(4))) float f32x4;

DI float b2f(unsigned short u) {
  union { unsigned int i; float f; } v; v.i = ((unsigned int)u) << 16; return v.f;
}
DI unsigned short f2b(float f) {
  union { float f; unsigned int i; } v; v.f = f;
  unsigned int r = v.i + 0x7fffu + ((v.i >> 16) & 1u);
  return (unsigned short)(r >> 16);
}
DI float sigm(float x) { return 1.0f / (1.0f + expf(-x)); }
DI float ldf(const void* p, size_t i, int f32f) {
  return f32f ? ((const float*)p)[i] : b2f(((const unsigned short*)p)[i]);
}
DI void stf(void* p, size_t i, float v, int f32f) {
  if (f32f) ((float*)p)[i] = v; else ((unsigned short*)p)[i] = f2b(v);
}
DI unsigned int ald(const unsigned int* p) {
  return __hip_atomic_load(p, __ATOMIC_RELAXED, __HIP_MEMORY_SCOPE_AGENT);
}
DI float aldf(const float* p) {
  return __hip_atomic_load(p, __ATOMIC_RELAXED, __HIP_MEMORY_SCOPE_AGENT);
}
DI void ast(unsigned int* p, unsigned int v) {
  __hip_atomic_store(p, v, __ATOMIC_RELAXED, __HIP_MEMORY_SCOPE_AGENT);
}
DI void astf(float* p, float v) {
  __hip_atomic_store(p, v, __ATOMIC_RELAXED, __HIP_MEMORY_SCOPE_AGENT);
}

__global__ void detect_k(const void* art, int* flag) {
  int tid = threadIdx.x;
  float x = ((const float*)art)[tid + 1024];
  float a = fabsf(x);
  int sane = (x == 0.0f) || (a > 1e-8f && a < 1e4f);
  unsigned long long m = __ballot(sane);
  __shared__ int cnt[4];
  if ((tid & 63) == 0) cnt[tid >> 6] = __popcll(m);
  __syncthreads();
  if (tid == 0) flag[0] = (cnt[0] + cnt[1] + cnt[2] + cnt[3] > 128) ? 1 : 0;
}

__global__ void fill_sig_k(unsigned short* o, int n) {
  int g = blockIdx.x * 256 + threadIdx.x;
  if (g < n) o[g] = 0x42F6;
}

__global__ void pack_gate_k(const void* __restrict__ W,
                            unsigned short* __restrict__ pk, const int* dtf) {
  int f32f = dtf[0];
  int g = blockIdx.x * 256 + threadIdx.x;
  if (g >= (GD * HID) / 8) return;
  int lane = g & 63;
  int kk = (g >> 6) & 15;
  int tile = g >> 10;
  int p = tile * 16 + (lane & 15);
  int nloc = p & 63, blk = p >> 6;
  int orow = (nloc >> 4) * HID + blk * 16 + (nloc & 15);
  int k = kk * 32 + (lane >> 4) * 8;
  unsigned short tmp[8];
#pragma unroll
  for (int j = 0; j < 8; ++j) tmp[j] = f2b(ldf(W, (size_t)orow * HID + k + j, f32f));
  *(uint4*)(pk + (size_t)g * 8) = *(uint4*)tmp;
}

// pack_gate for an internal f32 matrix (Wfold)
__global__ void pack_gate_f32_k(const float* __restrict__ W,
                                unsigned short* __restrict__ pk) {
  int g = blockIdx.x * 256 + threadIdx.x;
  if (g >= (GD * HID) / 8) return;
  int lane = g & 63;
  int kk = (g >> 6) & 15;
  int tile = g >> 10;
  int p = tile * 16 + (lane & 15);
  int nloc = p & 63, blk = p >> 6;
  int orow = (nloc >> 4) * HID + blk * 16 + (nloc & 15);
  int k = kk * 32 + (lane >> 4) * 8;
  unsigned short tmp[8];
#pragma unroll
  for (int j = 0; j < 8; ++j) tmp[j] = f2b(W[(size_t)orow * HID + k + j]);
  *(uint4*)(pk + (size_t)g * 8) = *(uint4*)tmp;
}

__global__ void pack_wm_k(const void* __restrict__ wm,
                          unsigned short* __restrict__ pk, const int* dtf) {
  int f32f = dtf[0];
  int g = blockIdx.x * 256 + threadIdx.x;
  if (g >= 32 * 32 * 64) return;
  int lane = g & 63;
  int kk = (g >> 6) & 31;
  int nt = g >> 11;
  int col = nt * 16 + (lane & 15);
  int kb = kk * 32 + (lane >> 4) * 8;
  unsigned short tmp[8];
#pragma unroll
  for (int j = 0; j < 8; ++j) tmp[j] = f2b(ldf(wm, (size_t)(kb + j) * HID + col, f32f));
  *(uint4*)(pk + (size_t)g * 8) = *(uint4*)tmp;
}

// Generic B-pack: W[K][N] row-major -> pk[(nt*(K/32)+kk)*64+lane][8]
__global__ void pack_bn_k(const void* __restrict__ W, unsigned short* __restrict__ pk,
                          int K, int N, int total, const int* dtf) {
  int f32f = dtf[0];
  int g = blockIdx.x * 256 + threadIdx.x;
  if (g >= total) return;
  int lane = g & 63;
  int KK = K >> 5;
  int t = g >> 6;
  int kk = t % KK;
  int nt = t / KK;
  int col = nt * 16 + (lane & 15);
  int kb = kk * 32 + (lane >> 4) * 8;
  unsigned short tmp[8];
#pragma unroll
  for (int j = 0; j < 8; ++j) tmp[j] = f2b(ldf(W, (size_t)(kb + j) * N + col, f32f));
  *(uint4*)(pk + (size_t)g * 8) = *(uint4*)tmp;
}

__global__ void pack_bf16_k(const void* __restrict__ src,
                            unsigned short* __restrict__ dst, int n, const int* dtf) {
  int f32f = dtf[0];
  int g = blockIdx.x * 256 + threadIdx.x;
  if (g < n) dst[g] = f2b(ldf(src, g, f32f));
}

// W2[512 kz][256 m] -> W2T[256 m][512 kz] f32 (one-shot, 512 KB)
__global__ void w2t_k(const void* __restrict__ W2, float* __restrict__ w2t,
                      const int* dtf) {
  int f32f = dtf[0];
  int g = blockIdx.x * 256 + threadIdx.x;   // 512 blocks -> 131072
  if (g >= 512 * 256) return;
  int kz = g >> 8, m = g & 255;             // coalesced read of W2 row kz
  w2t[(size_t)m * 512 + kz] = ldf(W2, (size_t)kz * 256 + m, f32f);
}

// Wfold[g][kz] = sum_m Wih[g][256+m] * W2T[m][kz]  — coalesced W2T stream
__global__ void fold2_k(const void* __restrict__ dWx, const float* __restrict__ w2t,
                        float* __restrict__ wf, const int* dtf) {
  int f32f = dtf[0];
  __shared__ float arow[256];
  int g = blockIdx.x;            // 0..2047
  int tid = threadIdx.x;         // 0..255
  arow[tid] = ldf(dWx, (size_t)g * 512 + 256 + tid, f32f);
  __syncthreads();
  float a0 = 0.f, a1 = 0.f;
#pragma unroll 8
  for (int m = 0; m < 256; ++m) {
    float a = arow[m];
    a0 += a * w2t[(size_t)m * 512 + tid];          // block reads 2KB contiguous
    a1 += a * w2t[(size_t)m * 512 + tid + 256];
  }
  wf[(size_t)g * 512 + tid] = a0;
  wf[(size_t)g * 512 + tid + 256] = a1;
}

// ge[i][g] = sum_m emb[SPECIAL+i][m] * Wih[g][m]   (i in 0..63)
__global__ void ge_k(const void* __restrict__ emb, const void* __restrict__ dWx,
                     float* __restrict__ ge, const int* dtf) {
  int f32f = dtf[0];
  int idx = blockIdx.x * 256 + threadIdx.x;   // 512 blocks -> 131072
  int i = idx >> 11, g = idx & 2047;
  float a = 0.f;
#pragma unroll 8
  for (int m = 0; m < 256; ++m)
    a += ldf(emb, (size_t)(SPECIAL + i) * 256 + m, f32f) *
         ldf(dWx, (size_t)g * 512 + m, f32f);
  ge[(size_t)i * 2048 + g] = a;
}

// ---------------------------------------------------------------------------
// Persistent bidirectional encoder (R14 software pipeline — proven).
// ---------------------------------------------------------------------------
__global__ __launch_bounds__(256, 1) void enc_all_k(
    const unsigned short* __restrict__ artb,
    unsigned short* __restrict__ outF, unsigned short* __restrict__ outB,
    const unsigned short* __restrict__ hIF, const unsigned short* __restrict__ hIB,
    float* __restrict__ cF, float* __restrict__ cB,
    const unsigned short* __restrict__ pkXF, const unsigned short* __restrict__ pkHF,
    const unsigned short* __restrict__ pkXB, const unsigned short* __restrict__ pkHB,
    const void* __restrict__ bF, const void* __restrict__ bB,
    int* __restrict__ bar, const int* dtf) {
  const int f32f = dtf[0];
  const int blk = blockIdx.x;
  const int dir = blk >> 5;
  const int blk16 = blk & 31;
  const int tid = threadIdx.x;
  const int lane = tid & 63;
  const int wv = tid >> 6;
  const int tile = blk16 * 4 + wv;

  __shared__ unsigned short lstage[BATCH * HID];
  __shared__ float gbuf[BATCH * 68];

  const unsigned short* pkX = dir ? pkXB : pkXF;
  const unsigned short* pkH = dir ? pkHB : pkHF;
  const void* bias = dir ? bB : bF;
  unsigned short* out = dir ? outB : outF;
  const unsigned short* hI = dir ? hIB : hIF;
  float* cg = dir ? cB : cF;
  int* flp = bar + dir * 32 * FLAG_STRIDE;

  bf16x8 wx[16], wh[16];
  {
    const unsigned short* px = pkX + ((size_t)tile * 16 * 64 + lane) * 8;
    const unsigned short* ph = pkH + ((size_t)tile * 16 * 64 + lane) * 8;
#pragma unroll
    for (int kk = 0; kk < 16; ++kk) {
      wx[kk] = *(const bf16x8*)(px + (size_t)kk * 64 * 8);
      wh[kk] = *(const bf16x8*)(ph + (size_t)kk * 64 * 8);
    }
  }
  const int gb = tid >> 3;
  const int gj = (tid & 7) * 2;
  float c0 = cg[gb * HID + blk16 * 16 + gj];
  float c1 = cg[gb * HID + blk16 * 16 + gj + 1];

  const int r0 = lane & 15;
  const int r1 = 16 + r0;
  const int kbb = (lane >> 4) * 8;
  const int nloc = wv * 16 + (lane & 15);
  const int orow = (nloc >> 4) * HID + blk16 * 16 + (nloc & 15);
  const float bv = ldf(bias, orow, f32f);

  f32x4 acc0 = {0.f, 0.f, 0.f, 0.f};
  f32x4 acc1 = {0.f, 0.f, 0.f, 0.f};

  {
    const int ts0 = dir ? (TS - 1) : 0;
#pragma unroll
    for (int it = 0; it < 8; ++it) {
      int ci = it * 256 + tid;
      int row = ci >> 6;
      int k8 = (ci & 63) << 3;
      uint4 v = *(const uint4*)(artb + (size_t)ts0 * BATCH * HID +
                                (size_t)row * HID + k8);
      unsigned off = (unsigned)(row * 1024 + ((k8 * 2) ^ ((row & 7) << 4)));
      *(uint4*)((char*)lstage + off) = v;
    }
    __syncthreads();
#pragma unroll
    for (int kk = 0; kk < 16; ++kk) {
      unsigned o0 = (unsigned)(r0 * 1024 + (((kk * 32 + kbb) * 2) ^ ((r0 & 7) << 4)));
      unsigned o1 = (unsigned)(r1 * 1024 + (((kk * 32 + kbb) * 2) ^ ((r0 & 7) << 4)));
      bf16x8 a0 = *(const bf16x8*)((const char*)lstage + o0);
      bf16x8 a1 = *(const bf16x8*)((const char*)lstage + o1);
      acc0 = __builtin_amdgcn_mfma_f32_16x16x32_bf16(a0, wx[kk], acc0, 0, 0, 0);
      acc1 = __builtin_amdgcn_mfma_f32_16x16x32_bf16(a1, wx[kk], acc1, 0, 0, 0);
    }
  }

  for (int t = 0; t < TS; ++t) {
    const int tsrc = dir ? (TS - 1 - t) : t;
    if (t > 0) {
      if (wv == 0) {
        const int target = t;
        for (;;) {
          int v = (lane < 32)
              ? __hip_atomic_load(flp + lane * FLAG_STRIDE, __ATOMIC_RELAXED,
                                  __HIP_MEMORY_SCOPE_AGENT)
              : 0x7fffffff;
          if (__all(v >= target)) break;
          __builtin_amdgcn_s_sleep(2);
        }
      }
      __syncthreads();
    }
    unsigned int* hu = (t == 0)
        ? (unsigned int*)hI
        : (unsigned int*)(out + (size_t)(tsrc + (dir ? 1 : -1)) * BATCH * HID);
    unsigned int hreg[32];
#pragma unroll
    for (int it = 0; it < 32; ++it) hreg[it] = ald(hu + it * 256 + tid);
    __syncthreads();
#pragma unroll
    for (int it = 0; it < 32; ++it) {
      int dw = it * 256 + tid;
      int row = dw >> 8;
      unsigned lb = (unsigned)(row * 1024 +
                               (((dw & 252) << 2) ^ ((row & 7) << 4)) +
                               ((dw & 3) << 2));
      *(unsigned int*)((char*)lstage + lb) = hreg[it];
    }
    __syncthreads();
#pragma unroll
    for (int kk = 0; kk < 16; ++kk) {
      unsigned o0 = (unsigned)(r0 * 1024 + (((kk * 32 + kbb) * 2) ^ ((r0 & 7) << 4)));
      unsigned o1 = (unsigned)(r1 * 1024 + (((kk * 32 + kbb) * 2) ^ ((r0 & 7) << 4)));
      bf16x8 a0 = *(const bf16x8*)((const char*)lstage + o0);
      bf16x8 a1 = *(const bf16x8*)((const char*)lstage + o1);
      acc0 = __builtin_amdgcn_mfma_f32_16x16x32_bf16(a0, wh[kk], acc0, 0, 0, 0);
      acc1 = __builtin_amdgcn_mfma_f32_16x16x32_bf16(a1, wh[kk], acc1, 0, 0, 0);
    }
#pragma unroll
    for (int r = 0; r < 4; ++r) {
      int brow = (lane >> 4) * 4 + r;
      gbuf[brow * 68 + nloc] = acc0[r] + bv;
      gbuf[(16 + brow) * 68 + nloc] = acc1[r] + bv;
    }
    __syncthreads();
    {
      float gi0 = gbuf[gb * 68 + gj],      gf0 = gbuf[gb * 68 + 16 + gj];
      float gg0 = gbuf[gb * 68 + 32 + gj], go0 = gbuf[gb * 68 + 48 + gj];
      float gi1 = gbuf[gb * 68 + gj + 1],      gf1 = gbuf[gb * 68 + 16 + gj + 1];
      float gg1 = gbuf[gb * 68 + 32 + gj + 1], go1 = gbuf[gb * 68 + 48 + gj + 1];
      float cn0 = sigm(gf0) * c0 + sigm(gi0) * tanhf(gg0); c0 = cn0;
      float cn1 = sigm(gf1) * c1 + sigm(gi1) * tanhf(gg1); c1 = cn1;
      unsigned int hv = (unsigned int)f2b(sigm(go0) * tanhf(cn0)) |
                        ((unsigned int)f2b(sigm(go1) * tanhf(cn1)) << 16);
      ast((unsigned int*)out + (size_t)tsrc * (BATCH * HID / 2) +
              gb * (HID / 2) + blk16 * 8 + (tid & 7), hv);
    }
    if (t + 1 < TS) {
      __syncthreads();
      if (wv == 0 && lane == 0)
        __hip_atomic_store(flp + blk16 * FLAG_STRIDE, t + 1,
                           __ATOMIC_RELAXED, __HIP_MEMORY_SCOPE_AGENT);
      const int tn = dir ? (TS - 2 - t) : (t + 1);
#pragma unroll
      for (int it = 0; it < 8; ++it) {
        int ci = it * 256 + tid;
        int row = ci >> 6;
        int k8 = (ci & 63) << 3;
        uint4 v = *(const uint4*)(artb + (size_t)tn * BATCH * HID +
                                  (size_t)row * HID + k8);
        unsigned off = (unsigned)(row * 1024 + ((k8 * 2) ^ ((row & 7) << 4)));
        *(uint4*)((char*)lstage + off) = v;
      }
      __syncthreads();
      acc0 = (f32x4){0.f, 0.f, 0.f, 0.f};
      acc1 = (f32x4){0.f, 0.f, 0.f, 0.f};
#pragma unroll
      for (int kk = 0; kk < 16; ++kk) {
        unsigned o0 = (unsigned)(r0 * 1024 + (((kk * 32 + kbb) * 2) ^ ((r0 & 7) << 4)));
        unsigned o1 = (unsigned)(r1 * 1024 + (((kk * 32 + kbb) * 2) ^ ((r0 & 7) << 4)));
        bf16x8 a0 = *(const bf16x8*)((const char*)lstage + o0);
        bf16x8 a1 = *(const bf16x8*)((const char*)lstage + o1);
        acc0 = __builtin_amdgcn_mfma_f32_16x16x32_bf16(a0, wx[kk], acc0, 0, 0, 0);
        acc1 = __builtin_amdgcn_mfma_f32_16x16x32_bf16(a1, wx[kk], acc1, 0, 0, 0);
      }
    }
  }
  cg[gb * HID + blk16 * 16 + gj] = c0;
  cg[gb * HID + blk16 * 16 + gj + 1] = c1;
}

// ---------------------------------------------------------------------------
// Persistent fused decoder (R16 — proven): 4 barriers/step, folded W2.
// ---------------------------------------------------------------------------
__global__ __launch_bounds__(512, 1) void dec_all_k(
    unsigned short* __restrict__ hd0, unsigned short* __restrict__ hd1,
    const float* __restrict__ cdec,
    const unsigned short* __restrict__ pkZ,
    const unsigned short* __restrict__ pkH,
    const void* __restrict__ dbias,
    const float* __restrict__ geb,
    const unsigned short* __restrict__ att,
    const unsigned short* __restrict__ pkq,
    const unsigned short* __restrict__ pkw1,
    const unsigned short* __restrict__ b1p,
    const unsigned short* __restrict__ pkw2,
    const int* __restrict__ lens,
    void* __restrict__ dout,
    float* __restrict__ qg,
    unsigned int* __restrict__ ctxb,
    unsigned int* __restrict__ zb,
    int* __restrict__ flags, const int* dtf) {
  const int f32f = dtf[0];
  const int blk = blockIdx.x;
  const int tid = threadIdx.x;
  const int lane = tid & 63;
  const int wv = tid >> 6;
  __shared__ __align__(16) char smem[49152];

  const int gb = tid >> 3;
  const int gj = (tid & 7) * 2;
  const int r0 = lane & 15;
  const int r1 = 16 + r0;
  const int kbb = (lane >> 4) * 8;
  const int nloc = wv * 16 + (lane & 15);
  float c0 = 0.f, c1 = 0.f, bv = 0.f;
  int orow = 0;
  bf16x8 cwz[16], cwh[16];
  if (tid < 256) {
    c0 = cdec[gb * HID + blk * 16 + gj];
    c1 = cdec[gb * HID + blk * 16 + gj + 1];
    orow = (nloc >> 4) * HID + blk * 16 + (nloc & 15);
    bv = ldf(dbias, orow, f32f);
    const int tile = blk * 4 + wv;
    const unsigned short* pz = pkZ + ((size_t)tile * 16 * 64 + lane) * 8;
    const unsigned short* ph = pkH + ((size_t)tile * 16 * 64 + lane) * 8;
#pragma unroll
    for (int kk = 0; kk < 16; ++kk) {
      cwz[kk] = *(const bf16x8*)(pz + (size_t)kk * 64 * 8);
      cwh[kk] = *(const bf16x8*)(ph + (size_t)kk * 64 * 8);
    }
  }

  int ep = 0;
  auto gbar = [&]() {
    __syncthreads();
    ++ep;
    if (wv == 0) {
      if (lane == 0)
        __hip_atomic_store(flags + blk * FLAG_STRIDE, ep, __ATOMIC_RELAXED,
                           __HIP_MEMORY_SCOPE_AGENT);
      for (;;) {
        int v = (lane < 32)
            ? __hip_atomic_load(flags + lane * FLAG_STRIDE, __ATOMIC_RELAXED,
                                __HIP_MEMORY_SCOPE_AGENT)
            : 0x7fffffff;
        if (__all(v >= ep)) break;
        __builtin_amdgcn_s_sleep(2);
      }
    }
    __syncthreads();
  };

  auto stage8k = [&](const unsigned int* src, unsigned short* lstage) {
    unsigned int rg[16];
#pragma unroll
    for (int it = 0; it < 16; ++it) rg[it] = ald(src + it * 512 + tid);
#pragma unroll
    for (int it = 0; it < 16; ++it) {
      int dw = it * 512 + tid;
      int row = dw >> 8;
      unsigned lb = (unsigned)(row * 1024 +
                               (((dw & 252) << 2) ^ ((row & 7) << 4)) +
                               ((dw & 3) << 2));
      *(unsigned int*)((char*)lstage + lb) = rg[it];
    }
  };

  auto afrag = [&](const unsigned short* lstage, int kk, bf16x8& a0, bf16x8& a1) {
    unsigned o0 = (unsigned)(r0 * 1024 + (((kk * 32 + kbb) * 2) ^ ((r0 & 7) << 4)));
    unsigned o1 = (unsigned)(r1 * 1024 + (((kk * 32 + kbb) * 2) ^ ((r0 & 7) << 4)));
    a0 = *(const bf16x8*)((const char*)lstage + o0);
    a1 = *(const bf16x8*)((const char*)lstage + o1);
  };

  for (int i = 0; i < TG; ++i) {
    unsigned short* hin = (i & 1) ? hd1 : hd0;
    unsigned short* hout = (i & 1) ? hd0 : hd1;
    f32x4 zacc0 = {0.f, 0.f, 0.f, 0.f};
    f32x4 zacc1 = {0.f, 0.f, 0.f, 0.f};

    // ===== P1: cell — gates = ge[i] + z_prev@Wfold + h@Whh (waves 0-3) =====
    {
      unsigned short* lstage = (unsigned short*)smem;
      float* gbuf = (float*)(smem + 32768);
      f32x4 acc0 = {0.f, 0.f, 0.f, 0.f};
      f32x4 acc1 = {0.f, 0.f, 0.f, 0.f};
      unsigned int hreg[32];
      if (tid < 256) {
        unsigned int zreg[32];
#pragma unroll
        for (int it = 0; it < 32; ++it) zreg[it] = ald(zb + it * 256 + tid);
#pragma unroll
        for (int it = 0; it < 32; ++it) {
          int dw = it * 256 + tid;
          int row = dw >> 8;
          unsigned lb = (unsigned)(row * 1024 +
                                   (((dw & 252) << 2) ^ ((row & 7) << 4)) +
                                   ((dw & 3) << 2));
          *(unsigned int*)((char*)lstage + lb) = zreg[it];
        }
      }
      __syncthreads();
      if (tid < 256) {
        const unsigned int* hu = (const unsigned int*)hin;
#pragma unroll
        for (int it = 0; it < 32; ++it) hreg[it] = ald(hu + it * 256 + tid);
#pragma unroll
        for (int kk = 0; kk < 16; ++kk) {
          bf16x8 a0, a1;
          afrag(lstage, kk, a0, a1);
          acc0 = __builtin_amdgcn_mfma_f32_16x16x32_bf16(a0, cwz[kk], acc0, 0, 0, 0);
          acc1 = __builtin_amdgcn_mfma_f32_16x16x32_bf16(a1, cwz[kk], acc1, 0, 0, 0);
        }
      }
      __syncthreads();
      if (tid < 256) {
#pragma unroll
        for (int it = 0; it < 32; ++it) {
          int dw = it * 256 + tid;
          int row = dw >> 8;
          unsigned lb = (unsigned)(row * 1024 +
                                   (((dw & 252) << 2) ^ ((row & 7) << 4)) +
                                   ((dw & 3) << 2));
          *(unsigned int*)((char*)lstage + lb) = hreg[it];
        }
      }
      __syncthreads();
      if (tid < 256) {
#pragma unroll
        for (int kk = 0; kk < 16; ++kk) {
          bf16x8 a0, a1;
          afrag(lstage, kk, a0, a1);
          acc0 = __builtin_amdgcn_mfma_f32_16x16x32_bf16(a0, cwh[kk], acc0, 0, 0, 0);
          acc1 = __builtin_amdgcn_mfma_f32_16x16x32_bf16(a1, cwh[kk], acc1, 0, 0, 0);
        }
        float gev = geb[(size_t)i * 2048 + orow];
#pragma unroll
        for (int r = 0; r < 4; ++r) {
          int brow = (lane >> 4) * 4 + r;
          gbuf[brow * 68 + nloc] = acc0[r] + bv + gev;
          gbuf[(16 + brow) * 68 + nloc] = acc1[r] + bv + gev;
        }
      }
      __syncthreads();
      if (tid < 256) {
        float gi0 = gbuf[gb * 68 + gj],      gf0 = gbuf[gb * 68 + 16 + gj];
        float gg0 = gbuf[gb * 68 + 32 + gj], go0 = gbuf[gb * 68 + 48 + gj];
        float gi1 = gbuf[gb * 68 + gj + 1],      gf1 = gbuf[gb * 68 + 16 + gj + 1];
        float gg1 = gbuf[gb * 68 + 32 + gj + 1], go1 = gbuf[gb * 68 + 48 + gj + 1];
        float cn0 = sigm(gf0) * c0 + sigm(gi0) * tanhf(gg0); c0 = cn0;
        float cn1 = sigm(gf1) * c1 + sigm(gi1) * tanhf(gg1); c1 = cn1;
        float hn0 = sigm(go0) * tanhf(cn0);
        float hn1 = sigm(go1) * tanhf(cn1);
        ast((unsigned int*)hout + gb * (HID / 2) + blk * 8 + (tid & 7),
            (unsigned int)f2b(hn0) | ((unsigned int)f2b(hn1) << 16));
        size_t e0 = ((size_t)gb * TG + i) * HID + blk * 16 + gj;
        stf(dout, OFF_H + e0, hn0, f32f);
        stf(dout, OFF_H + e0 + 1, hn1, f32f);
        stf(dout, OFF_C + e0, cn0, f32f);
        stf(dout, OFF_C + e0 + 1, cn1, f32f);
      }
    }
    gbar();   // b1: h ready

    // ====== P2: q = h@wq AND z-h-half = h@W1[:512] (partials in regs) ======
    {
      unsigned short* lstage = (unsigned short*)smem;
      float* part = (float*)(smem + 32768);
      stage8k((const unsigned int*)hout, lstage);
      __syncthreads();
      f32x4 acc0 = {0.f, 0.f, 0.f, 0.f};
      f32x4 acc1 = {0.f, 0.f, 0.f, 0.f};
#pragma unroll
      for (int j = 0; j < 2; ++j) {
        int kk = wv * 2 + j;
        bf16x8 a0, a1;
        afrag(lstage, kk, a0, a1);
        bf16x8 bq = *(const bf16x8*)(pkq + ((size_t)(blk * 16 + kk) * 64 + lane) * 8);
        acc0 = __builtin_amdgcn_mfma_f32_16x16x32_bf16(a0, bq, acc0, 0, 0, 0);
        acc1 = __builtin_amdgcn_mfma_f32_16x16x32_bf16(a1, bq, acc1, 0, 0, 0);
        bf16x8 bw = *(const bf16x8*)(pkw1 + ((size_t)(blk * 32 + kk) * 64 + lane) * 8);
        zacc0 = __builtin_amdgcn_mfma_f32_16x16x32_bf16(a0, bw, zacc0, 0, 0, 0);
        zacc1 = __builtin_amdgcn_mfma_f32_16x16x32_bf16(a1, bw, zacc1, 0, 0, 0);
      }
#pragma unroll
      for (int r = 0; r < 4; ++r) {
        int m0 = (lane >> 4) * 4 + r;
        part[wv * 512 + m0 * 16 + (lane & 15)] = acc0[r];
        part[wv * 512 + (m0 + 16) * 16 + (lane & 15)] = acc1[r];
      }
      __syncthreads();
      {
        float s = 0.f;
#pragma unroll
        for (int w = 0; w < 8; ++w) s += part[w * 512 + tid];
        int bb2 = tid >> 4, cl = tid & 15;
        astf(qg + (size_t)bb2 * HID + blk * 16 + cl, s);
      }
    }
    gbar();   // b2: q ready

    // ============ P3: flash score+ctx, 4-row unroll (block = batch) ========
    {
      const int b = blk;
      const int len = lens[b];
      float* cred = (float*)smem;
      float* mwl  = (float*)(smem + 16384);
      float* lwl  = (float*)(smem + 16448);
      float* qf   = (float*)(smem + 16512);
      float* ctxf = (float*)(smem + 18560);
      qf[tid] = aldf(qg + (size_t)b * HID + tid);
      __syncthreads();
      float qv[8];
#pragma unroll
      for (int e = 0; e < 8; ++e) qv[e] = qf[lane * 8 + e];
      float m = -1e30f, l = 0.f;
      float ca[8] = {0.f, 0.f, 0.f, 0.f, 0.f, 0.f, 0.f, 0.f};
      const unsigned short* ab = att + ((size_t)b * TS + wv * 128) * HID + lane * 8;
      for (int tt = 0; tt < 128; tt += 4) {
        int t = wv * 128 + tt;
        bf16x8 rr0 = *(const bf16x8*)(ab + (size_t)(tt + 0) * HID);
        bf16x8 rr1 = *(const bf16x8*)(ab + (size_t)(tt + 1) * HID);
        bf16x8 rr2 = *(const bf16x8*)(ab + (size_t)(tt + 2) * HID);
        bf16x8 rr3 = *(const bf16x8*)(ab + (size_t)(tt + 3) * HID);
        float s0 = 0.f, s1 = 0.f, s2 = 0.f, s3 = 0.f;
#pragma unroll
        for (int e = 0; e < 8; ++e) {
          float q = qv[e];
          s0 += q * b2f(((const unsigned short*)&rr0)[e]);
          s1 += q * b2f(((const unsigned short*)&rr1)[e]);
          s2 += q * b2f(((const unsigned short*)&rr2)[e]);
          s3 += q * b2f(((const unsigned short*)&rr3)[e]);
        }
        for (int o = 32; o; o >>= 1) {
          s0 += __shfl_xor(s0, o, 64); s1 += __shfl_xor(s1, o, 64);
          s2 += __shfl_xor(s2, o, 64); s3 += __shfl_xor(s3, o, 64);
        }
        bool v0 = (t < len), v1 = (t + 1 < len), v2 = (t + 2 < len), v3 = (t + 3 < len);
        float smax = fmaxf(fmaxf(v0 ? s0 : -1e30f, v1 ? s1 : -1e30f),
                           fmaxf(v2 ? s2 : -1e30f, v3 ? s3 : -1e30f));
        if (smax > m) {
          float sc2 = expf(m - smax);
          l *= sc2;
#pragma unroll
          for (int e = 0; e < 8; ++e) ca[e] *= sc2;
          m = smax;
        }
        if (v0) { float p = expf(s0 - m); l += p;
#pragma unroll
          for (int e = 0; e < 8; ++e) ca[e] += p * b2f(((const unsigned short*)&rr0)[e]); }
        if (v1) { float p = expf(s1 - m); l += p;
#pragma unroll
          for (int e = 0; e < 8; ++e) ca[e] += p * b2f(((const unsigned short*)&rr1)[e]); }
        if (v2) { float p = expf(s2 - m); l += p;
#pragma unroll
          for (int e = 0; e < 8; ++e) ca[e] += p * b2f(((const unsigned short*)&rr2)[e]); }
        if (v3) { float p = expf(s3 - m); l += p;
#pragma unroll
          for (int e = 0; e < 8; ++e) ca[e] += p * b2f(((const unsigned short*)&rr3)[e]); }
      }
#pragma unroll
      for (int e = 0; e < 8; ++e) cred[wv * 512 + lane * 8 + e] = ca[e];
      if (lane == 0) { mwl[wv] = m; lwl[wv] = l; }
      __syncthreads();
      {
        float M = -1e30f;
#pragma unroll
        for (int w = 0; w < 8; ++w) M = fmaxf(M, mwl[w]);
        float L = 0.f, s = 0.f;
#pragma unroll
        for (int w = 0; w < 8; ++w) {
          float sc2 = expf(mwl[w] - M);
          L += lwl[w] * sc2;
          s += cred[w * 512 + tid] * sc2;
        }
        ctxf[tid] = s / L;
      }
      __syncthreads();
      if (tid < 256) {
        unsigned int d = (unsigned int)f2b(ctxf[2 * tid]) |
                         ((unsigned int)f2b(ctxf[2 * tid + 1]) << 16);
        ast(ctxb + b * 256 + tid, d);
      }
    }
    gbar();   // b3: ctx ready

    // ====== P4: z ctx-half adds onto carried partials; tanh -> zb bf16 =====
    {
      unsigned short* lstage = (unsigned short*)smem;
      float* part = (float*)(smem + 32768);
      stage8k(ctxb, lstage);
      __syncthreads();
#pragma unroll
      for (int j = 0; j < 2; ++j) {
        int kkl = wv * 2 + j;
        bf16x8 a0, a1;
        afrag(lstage, kkl, a0, a1);
        bf16x8 bb = *(const bf16x8*)(pkw1 + ((size_t)(blk * 32 + 16 + kkl) * 64 + lane) * 8);
        zacc0 = __builtin_amdgcn_mfma_f32_16x16x32_bf16(a0, bb, zacc0, 0, 0, 0);
        zacc1 = __builtin_amdgcn_mfma_f32_16x16x32_bf16(a1, bb, zacc1, 0, 0, 0);
      }
      __syncthreads();
#pragma unroll
      for (int r = 0; r < 4; ++r) {
        int m0 = (lane >> 4) * 4 + r;
        part[wv * 512 + m0 * 16 + (lane & 15)] = zacc0[r];
        part[wv * 512 + (m0 + 16) * 16 + (lane & 15)] = zacc1[r];
      }
      __syncthreads();
      {
        float s = 0.f;
#pragma unroll
        for (int w = 0; w < 8; ++w) s += part[w * 512 + tid];
        int bb2 = tid >> 4, cl = tid & 15;
        int col = blk * 16 + cl;
        float zv = tanhf(b2f(b1p[col]) + s);
        unsigned short me = f2b(zv);
        int other = __shfl_xor((int)me, 1);
        if (!(tid & 1))
          ast(zb + bb2 * 256 + (col >> 1),
              (unsigned int)me | ((unsigned int)(other & 0xffff) << 16));
      }
    }
    gbar();   // b4: z ready (also gates next P1)

    // ====== P5: out = z @ W2 (blocks 0..15), NO trailing barrier ===========
    if (blk < 16) {
      unsigned short* lstage = (unsigned short*)smem;
      float* part = (float*)(smem + 32768);
      stage8k(zb, lstage);
      __syncthreads();
      f32x4 acc0 = {0.f, 0.f, 0.f, 0.f};
      f32x4 acc1 = {0.f, 0.f, 0.f, 0.f};
#pragma unroll
      for (int j = 0; j < 2; ++j) {
        int kk = wv * 2 + j;
        bf16x8 a0, a1;
        afrag(lstage, kk, a0, a1);
        bf16x8 bb = *(const bf16x8*)(pkw2 + ((size_t)(blk * 16 + kk) * 64 + lane) * 8);
        acc0 = __builtin_amdgcn_mfma_f32_16x16x32_bf16(a0, bb, acc0, 0, 0, 0);
        acc1 = __builtin_amdgcn_mfma_f32_16x16x32_bf16(a1, bb, acc1, 0, 0, 0);
      }
#pragma unroll
      for (int r = 0; r < 4; ++r) {
        int m0 = (lane >> 4) * 4 + r;
        part[wv * 512 + m0 * 16 + (lane & 15)] = acc0[r];
        part[wv * 512 + (m0 + 16) * 16 + (lane & 15)] = acc1[r];
      }
      __syncthreads();
      {
        float s = 0.f;
#pragma unroll
        for (int w = 0; w < 8; ++w) s += part[w * 512 + tid];
        int bb2 = tid >> 4, cl = tid & 15;
        int col = blk * 16 + cl;
        stf(dout, ((size_t)bb2 * TG + i) * EDIM + col, s, f32f);
      }
      __syncthreads();
    }
  }
}

__global__ __launch_bounds__(256) void attn_mm_k(
    const unsigned short* __restrict__ outF, const unsigned short* __restrict__ outB,
    const unsigned short* __restrict__ pkwm, unsigned short* __restrict__ att) {
  __shared__ char ldsA[4 * 1040];
  int bid = blockIdx.x;
  int bn = bid & 7, bm = bid >> 3;
  int tid = threadIdx.x, lane = tid & 63, wv = tid >> 6;
  int r0 = bm * 64;
  f32x4 acc[2][2] = {};
  int srow = tid >> 2, skb = tid & 3;
  int mt0 = (wv & 1) * 2, nt0 = (wv >> 1) * 2;
  for (int kk = 0; kk < 32; ++kk) {
    int kg = kk * 32 + skb * 8;
    const unsigned short* src = (kg < HID)
        ? (outF + (size_t)(r0 + srow) * HID + kg)
        : (outB + (size_t)(r0 + srow) * HID + (kg - HID));
    uint4 v = *(const uint4*)src;
    __syncthreads();
    *(uint4*)(ldsA + skb * 1040 + srow * 16) = v;
    __syncthreads();
    bf16x8 a[2], bb[2];
#pragma unroll
    for (int mi = 0; mi < 2; ++mi) {
      int rl = (mt0 + mi) * 16 + (lane & 15);
      a[mi] = *(const bf16x8*)(ldsA + (lane >> 4) * 1040 + rl * 16);
    }
#pragma unroll
    for (int nj = 0; nj < 2; ++nj) {
      int ntg = bn * 4 + nt0 + nj;
      bb[nj] = *(const bf16x8*)(pkwm + ((size_t)(ntg * 32 + kk) * 64 + lane) * 8);
    }
#pragma unroll
    for (int mi = 0; mi < 2; ++mi)
#pragma unroll
      for (int nj = 0; nj < 2; ++nj)
        acc[mi][nj] = __builtin_amdgcn_mfma_f32_16x16x32_bf16(a[mi], bb[nj], acc[mi][nj], 0, 0, 0);
  }
#pragma unroll
  for (int mi = 0; mi < 2; ++mi)
#pragma unroll
    for (int nj = 0; nj < 2; ++nj)
#pragma unroll
      for (int r = 0; r < 4; ++r) {
        int row = r0 + (mt0 + mi) * 16 + (lane >> 4) * 4 + r;
        int t = row >> 5, b = row & 31;
        int h = bn * 64 + (nt0 + nj) * 16 + (lane & 15);
        att[((size_t)b * TS + t) * HID + h] = f2b(acc[mi][nj][r]);
      }
}

__global__ void init_states_k(const void* __restrict__ ih, const void* __restrict__ ic,
                              unsigned short* hIF, unsigned short* hIB,
                              float* cF, float* cB, int* bar, const int* dtf) {
  int f32f = dtf[0];
  int g = blockIdx.x * 256 + threadIdx.x;
  if (g < (64 + 32) * FLAG_STRIDE)
    __hip_atomic_store(bar + g, 0, __ATOMIC_RELAXED, __HIP_MEMORY_SCOPE_AGENT);
  int b = g >> 9, j = g & 511;
  hIF[b * HID + j] = f2b(ldf(ih, j, f32f));
  hIB[b * HID + j] = f2b(ldf(ih, HID + j, f32f));
  cF[b * HID + j] = ldf(ic, j, f32f);
  cB[b * HID + j] = ldf(ic, HID + j, f32f);
}

// seqmean with 8-deep load ILP (4 rows x 2 cols in flight)
__global__ void seqmean_k(const unsigned short* __restrict__ att,
                          const int* __restrict__ lens, float* __restrict__ sm) {
  int b = blockIdx.x, tid = threadIdx.x;
  int len = lens[b];
  float s00 = 0.f, s01 = 0.f, s02 = 0.f, s03 = 0.f;
  float s10 = 0.f, s11 = 0.f, s12 = 0.f, s13 = 0.f;
  int t = 0;
  for (; t + 4 <= len; t += 4) {
    const unsigned short* r0 = att + ((size_t)b * TS + t) * HID;
    const unsigned short* r1 = r0 + HID;
    const unsigned short* r2 = r1 + HID;
    const unsigned short* r3 = r2 + HID;
    s00 += b2f(r0[tid]); s10 += b2f(r0[tid + 256]);
    s01 += b2f(r1[tid]); s11 += b2f(r1[tid + 256]);
    s02 += b2f(r2[tid]); s12 += b2f(r2[tid + 256]);
    s03 += b2f(r3[tid]); s13 += b2f(r3[tid + 256]);
  }
  for (; t < len; ++t) {
    const unsigned short* r0 = att + ((size_t)b * TS + t) * HID;
    s00 += b2f(r0[tid]); s10 += b2f(r0[tid + 256]);
  }
  float fl = (float)len;
  sm[b * HID + tid] = (s00 + s01 + s02 + s03) / fl;
  sm[b * HID + tid + 256] = (s10 + s11 + s12 + s13) / fl;
}

__global__ void mv_bb_k(const unsigned short* __restrict__ A1,
                        const unsigned short* __restrict__ A2,
                        const void* __restrict__ W, unsigned short* __restrict__ o,
                        const int* dtf) {
  int f32f = dtf[0];
  int g = blockIdx.x * 256 + threadIdx.x;
  int b = g >> 9, n = g & 511;
  float acc = 0.f;
  for (int k = 0; k < HID; ++k) acc += b2f(A1[b * HID + k]) * ldf(W, (size_t)k * HID + n, f32f);
  for (int k = 0; k < HID; ++k) acc += b2f(A2[b * HID + k]) * ldf(W, (size_t)(HID + k) * HID + n, f32f);
  o[b * HID + n] = f2b(acc);
}

__global__ void mv_ff_k(const float* __restrict__ A1, const float* __restrict__ A2,
                        const void* __restrict__ W, float* __restrict__ o, const int* dtf) {
  int f32f = dtf[0];
  int g = blockIdx.x * 256 + threadIdx.x;
  int b = g >> 9, n = g & 511;
  float acc = 0.f;
  for (int k = 0; k < HID; ++k) acc += A1[b * HID + k] * ldf(W, (size_t)k * HID + n, f32f);
  for (int k = 0; k < HID; ++k) acc += A2[b * HID + k] * ldf(W, (size_t)(HID + k) * HID + n, f32f);
  o[b * HID + n] = acc;
}

__global__ void proj1_k(const unsigned short* __restrict__ A1, const float* __restrict__ A2,
                        const void* __restrict__ W1p, const void* __restrict__ b1p,
                        unsigned short* __restrict__ z, const int* dtf) {
  int f32f = dtf[0];
  int g = blockIdx.x * 256 + threadIdx.x;
  int b = g >> 9, n = g & 511;
  float acc = ldf(b1p, n, f32f);
  for (int k = 0; k < HID; ++k) acc += b2f(A1[b * HID + k]) * ldf(W1p, (size_t)k * HID + n, f32f);
  for (int k = 0; k < HID; ++k) acc += A2[b * HID + k] * ldf(W1p, (size_t)(HID + k) * HID + n, f32f);
  z[b * HID + n] = f2b(tanhf(acc));
}

extern "C" void kernel_launch(void* const* d_in, const int* in_sizes, int n_in,
                              void* d_out, int out_size, void* d_ws, size_t ws_size,
                              hipStream_t stream) {
  (void)in_sizes; (void)n_in;
  const void* article = d_in[0];
  const int* art_lens = (const int*)d_in[1];
  const void* emb  = d_in[3];
  const void* eWxf = d_in[4]; const void* eWhf = d_in[5]; const void* ebf = d_in[6];
  const void* eWxb = d_in[7]; const void* eWhb = d_in[8]; const void* ebb = d_in[9];
  const void* initH = d_in[10]; const void* initC = d_in[11];
  const void* dhW = d_in[12]; const void* dcW = d_in[13];
  const void* wm = d_in[14]; const void* wq = d_in[15];
  const void* W1 = d_in[16]; const void* b1 = d_in[17]; const void* W2 = d_in[18];
  const void* dWx = d_in[19]; const void* dWh = d_in[20]; const void* db = d_in[21];

  char* ws = (char*)d_ws;
  size_t off = 0;
  auto take = [&](size_t bytes) -> char* {
    char* p = ws + off;
    off = (off + bytes + 255) & ~(size_t)255;
    return p;
  };
  int* dtf = (int*)take(4);
  int* bar = (int*)take((64 + 32) * FLAG_STRIDE * 4);
  unsigned short* pk_exf = (unsigned short*)take((size_t)GD * HID * 2);
  unsigned short* pk_ehf = (unsigned short*)take((size_t)GD * HID * 2);
  unsigned short* pk_exb = (unsigned short*)take((size_t)GD * HID * 2);
  unsigned short* pk_ehb = (unsigned short*)take((size_t)GD * HID * 2);
  unsigned short* pk_fold = (unsigned short*)take((size_t)GD * HID * 2);
  unsigned short* pk_dh  = (unsigned short*)take((size_t)GD * HID * 2);
  unsigned short* pk_wm  = (unsigned short*)take((size_t)1024 * HID * 2);
  unsigned short* pkq  = (unsigned short*)take((size_t)512 * 512 * 2);
  unsigned short* pkw1 = (unsigned short*)take((size_t)1024 * 512 * 2);
  unsigned short* b1p  = (unsigned short*)take((size_t)HID * 2);
  unsigned short* pkw2 = (unsigned short*)take((size_t)512 * 256 * 2);
  float* w2tf = (float*)take((size_t)256 * 512 * 4);
  float* wfoldf = (float*)take((size_t)GD * HID * 4);
  float* geb = (float*)take((size_t)TG * GD * 4);
  unsigned short* outF = (unsigned short*)take((size_t)TS * BATCH * HID * 2);
  unsigned short* outB = (unsigned short*)take((size_t)TS * BATCH * HID * 2);
  unsigned short* att  = (unsigned short*)take((size_t)BATCH * TS * HID * 2);
  unsigned short* hIF  = (unsigned short*)take((size_t)BATCH * HID * 2);
  unsigned short* hIB  = (unsigned short*)take((size_t)BATCH * HID * 2);
  float* cF = (float*)take((size_t)BATCH * HID * 4);
  float* cB = (float*)take((size_t)BATCH * HID * 4);
  unsigned short* hd0 = (unsigned short*)take((size_t)BATCH * HID * 2);
  unsigned short* hd1 = (unsigned short*)take((size_t)BATCH * HID * 2);
  float* cdec = (float*)take((size_t)BATCH * HID * 4);
  unsigned short* zbuf = (unsigned short*)take((size_t)BATCH * HID * 2);
  float* qg = (float*)take((size_t)BATCH * HID * 4);
  unsigned int* ctxb = (unsigned int*)take((size_t)BATCH * 256 * 4);
  float* sm = (float*)take((size_t)BATCH * HID * 4);

  if (off > ws_size) {
    fill_sig_k<<<(out_size + 255) / 256, 256, 0, stream>>>((unsigned short*)d_out, out_size);
    return;
  }

  unsigned short* artb = att;   // alias: article-bf16 live only during encoding

  detect_k<<<1, 256, 0, stream>>>(article, dtf);
  pack_gate_k<<<512, 256, 0, stream>>>(eWxf, pk_exf, dtf);
  pack_gate_k<<<512, 256, 0, stream>>>(eWhf, pk_ehf, dtf);
  pack_gate_k<<<512, 256, 0, stream>>>(eWxb, pk_exb, dtf);
  pack_gate_k<<<512, 256, 0, stream>>>(eWhb, pk_ehb, dtf);
  pack_gate_k<<<512, 256, 0, stream>>>(dWh, pk_dh, dtf);
  w2t_k<<<512, 256, 0, stream>>>(W2, w2tf, dtf);
  fold2_k<<<2048, 256, 0, stream>>>(dWx, w2tf, wfoldf, dtf);
  ge_k<<<512, 256, 0, stream>>>(emb, dWx, geb, dtf);
  pack_gate_f32_k<<<512, 256, 0, stream>>>(wfoldf, pk_fold);
  pack_wm_k<<<256, 256, 0, stream>>>(wm, pk_wm, dtf);
  pack_bn_k<<<128, 256, 0, stream>>>(wq, pkq, 512, 512, 32 * 16 * 64, dtf);
  pack_bn_k<<<256, 256, 0, stream>>>(W1, pkw1, 1024, 512, 32 * 32 * 64, dtf);
  pack_bn_k<<<64, 256, 0, stream>>>(W2, pkw2, 512, 256, 16 * 16 * 64, dtf);
  pack_bf16_k<<<2, 256, 0, stream>>>(b1, b1p, HID, dtf);
  pack_bf16_k<<<65536, 256, 0, stream>>>(article, artb, TS * BATCH * HID, dtf);
  init_states_k<<<64, 256, 0, stream>>>(initH, initC, hIF, hIB, cF, cB, bar, dtf);

  enc_all_k<<<64, 256, 0, stream>>>(artb, outF, outB, hIF, hIB, cF, cB,
                                    pk_exf, pk_ehf, pk_exb, pk_ehb, ebf, ebb,
                                    bar, dtf);

  attn_mm_k<<<4096, 256, 0, stream>>>(outF, outB, pk_wm, att);
  seqmean_k<<<32, 256, 0, stream>>>(att, art_lens, sm);
  mv_bb_k<<<64, 256, 0, stream>>>(outF + (size_t)(TS - 1) * BATCH * HID, outB, dhW, hd0, dtf);
  mv_ff_k<<<64, 256, 0, stream>>>(cF, cB, dcW, cdec, dtf);
  proj1_k<<<64, 256, 0, stream>>>(hd0, sm, W1, b1, zbuf, dtf);

  dec_all_k<<<32, 512, 0, stream>>>(hd0, hd1, cdec, pk_fold, pk_dh, db, geb,
                                    att, pkq, pkw1, b1p, pkw2, art_lens,
                                    d_out, qg, ctxb, (unsigned int*)zbuf,
                                    bar + 64 * FLAG_STRIDE, dtf);
}